// Round 4
// baseline (515.788 us; speedup 1.0000x reference)
//
#include <hip/hip_runtime.h>

__device__ __forceinline__ float frcp(float x){ return __builtin_amdgcn_rcpf(x); }
__device__ __forceinline__ float fexp2(float x){ return __builtin_amdgcn_exp2f(x); }
// sigmoid(x) = 1/(1+e^-x);  tanh(x) = 1 - 2/(e^{2x}+1)
__device__ __forceinline__ float sigf(float x){ return frcp(1.f + fexp2(-1.4426950408889634f*x)); }
__device__ __forceinline__ float tanh_(float x){ return 1.f - 2.f*frcp(1.f + fexp2(2.8853900817779268f*x)); }

// ---------------- embedding gather + concat -> x[b*128+t][128] fp32 ----------------
__global__ __launch_bounds__(256) void embed_kernel(
    const int* __restrict__ widx, const int* __restrict__ pidx,
    const float* __restrict__ wemb, const float* __restrict__ temb,
    float* __restrict__ x)
{
    int gid = blockIdx.x*256 + threadIdx.x;   // 262144 total
    int bt = gid >> 7, c = gid & 127;
    float v;
    if (c < 100) v = wemb[(size_t)widx[bt]*100 + c];
    else         v = temb[(size_t)pidx[bt]*28 + (c-100)];
    x[gid] = v;
}

// ---------------- w2[k] = -2*fc2_w[k]; S = sum(fc2_w) + fc2_b ----------------
__global__ void prep_kernel(const float* __restrict__ fc2w, const float* __restrict__ fc2b,
                            float* __restrict__ w2, float* __restrict__ Sp)
{
    __shared__ float red[128];
    int t = threadIdx.x;
    float w = (t < 100) ? fc2w[t] : 0.f;
    if (t < 100) w2[t] = -2.f*w;
    red[t] = w;
    __syncthreads();
    for (int s = 64; s > 0; s >>= 1) {
        if (t < s) red[t] += red[t+s];
        __syncthreads();
    }
    if (t == 0) Sp[0] = red[0] + fc2b[0];
}

// ---------------- generic C[m][n] = sum_k A[m][k]*B[n][k] (+biases) (opt exp(2x)) --------
// M fixed 2048 (grid.x=16, BM=128). grid.z selects B/bias/C set. BN=64, BK=16.
// permflag: output column p holds gate-row gr(p) = (p&3)*128 + (p>>2) (for LSTM layout).
__global__ __launch_bounds__(256) void gemm_kernel(
    const float* __restrict__ A, int K,
    const float* __restrict__ B0, const float* __restrict__ B1, int ldb,
    const float* __restrict__ bias0a, const float* __restrict__ bias0b,
    const float* __restrict__ bias1a, const float* __restrict__ bias1b,
    float* __restrict__ C0, float* __restrict__ C1, int ldc, int N,
    int expflag, int permflag)
{
    __shared__ float As[16][132];   // [k][m], pad 132 (16B-aligned rows)
    __shared__ float Bs[16][68];    // [k][n]
    const int z = blockIdx.z;
    const float* B  = z ? B1 : B0;
    const float* ba = z ? bias1a : bias0a;
    const float* bb = z ? bias1b : bias0b;
    float* C = z ? C1 : C0;
    const int m0 = blockIdx.x * 128;
    const int n0 = blockIdx.y * 64;
    const int tx = threadIdx.x;
    const int tm = tx & 15, tn = tx >> 4;       // 8x4 micro-tile
    const int arow = tx >> 1, akq = (tx & 1) * 8;
    const int brow = tx >> 2, bkq = (tx & 3) * 4;
    float acc[8][4];
    #pragma unroll
    for (int r=0;r<8;++r){
        #pragma unroll
        for (int c=0;c<4;++c) acc[r][c]=0.f; }
    const int bn = n0 + brow;
    const int brow_src = permflag ? ((bn & 3)*128 + (bn >> 2)) : bn;
    for (int k0 = 0; k0 < K; k0 += 16) {
        const float* ap = A + (size_t)(m0+arow)*K + k0 + akq;
        float4 a0 = *(const float4*)ap;
        float4 a1 = *(const float4*)(ap+4);
        float4 bv = make_float4(0.f,0.f,0.f,0.f);
        if (bn < N) {
            const float* bp = B + (size_t)brow_src*ldb + k0 + bkq;
            bv = *(const float4*)bp;
        }
        __syncthreads();
        As[akq+0][arow]=a0.x; As[akq+1][arow]=a0.y; As[akq+2][arow]=a0.z; As[akq+3][arow]=a0.w;
        As[akq+4][arow]=a1.x; As[akq+5][arow]=a1.y; As[akq+6][arow]=a1.z; As[akq+7][arow]=a1.w;
        Bs[bkq+0][brow]=bv.x; Bs[bkq+1][brow]=bv.y; Bs[bkq+2][brow]=bv.z; Bs[bkq+3][brow]=bv.w;
        __syncthreads();
        #pragma unroll
        for (int kk = 0; kk < 16; ++kk) {
            float4 av0 = *(const float4*)&As[kk][tm*8];
            float4 av1 = *(const float4*)&As[kk][tm*8+4];
            float4 bvv = *(const float4*)&Bs[kk][tn*4];
            float a[8] = {av0.x,av0.y,av0.z,av0.w,av1.x,av1.y,av1.z,av1.w};
            float b[4] = {bvv.x,bvv.y,bvv.z,bvv.w};
            #pragma unroll
            for (int r=0;r<8;++r){
                #pragma unroll
                for (int c=0;c<4;++c)
                    acc[r][c] = fmaf(a[r], b[c], acc[r][c]);
            }
        }
    }
    float bias[4];
    #pragma unroll
    for (int c=0;c<4;++c) {
        int n = n0 + tn*4 + c;
        int nsrc = permflag ? ((n & 3)*128 + (n >> 2)) : n;
        float v = 0.f;
        if (n < N) {
            if (ba) v += ba[nsrc];
            if (bb) v += bb[nsrc];
        }
        bias[c] = v;
    }
    #pragma unroll
    for (int r=0;r<8;++r) {
        int m = m0 + tm*8 + r;
        float v[4];
        #pragma unroll
        for (int c=0;c<4;++c) {
            float t = acc[r][c] + bias[c];
            if (expflag) t = fexp2(fminf(fmaxf(t,-40.f),40.f)*2.8853900817779268f); // e^{2t}
            v[c] = t;
        }
        int n = n0 + tn*4;
        if (n + 3 < N) {
            float4 st; st.x=v[0]; st.y=v[1]; st.z=v[2]; st.w=v[3];
            *(float4*)&C[(size_t)m*ldc + n] = st;
        } else {
            #pragma unroll
            for (int c=0;c<4;++c) if (n+c < N) C[(size_t)m*ldc + n + c] = v[c];
        }
    }
}

// ---------------- LSTM: one block per (b, dir); gate-interleaved thread map ----------------
// thread t: row r = t>>2, gate g = t&3 (i,f,g,o). Weight row gr = g*128 + r resident in VGPRs.
// Weights loaded VOLATILE: defeats LLVM's invariant-load rematerialization, which in rounds
// 2-3 re-issued the loads inside the step loop (VGPR_Count=100/120 instead of ~170).
// xp comes in pre-permuted (col p = gate row gr(p)). One barrier per step; h double-buffered.
__global__ __launch_bounds__(512)
__attribute__((amdgpu_waves_per_eu(2,2)))
void lstm_kernel(
    const float* __restrict__ xp,      // [dir][2048][512] permuted cols
    const float* __restrict__ whh_f, const float* __restrict__ whh_b,
    float* __restrict__ hcat)          // [16][128][256]
{
    const int b = blockIdx.x & 15;
    const int dir = blockIdx.x >> 4;
    const int t = threadIdx.x;
    const int gate = t & 3, r = t >> 2;
    const int lane = t & 63, qbase = lane & ~3;
    const float* whh = dir ? whh_b : whh_f;
    // per-lane activation constants: sig(x)=1/(1+2^(-x*log2e)); tanh(x)=1-2/(1+2^(2x*log2e))
    const float kexp = (gate == 2) ? 2.8853900817779268f : -1.4426950408889634f;
    const float mA   = (gate == 2) ? -2.f : 1.f;
    const float mB   = (gate == 2) ?  1.f : 0.f;
    float w[128];
    {
        const volatile float* wr = (const volatile float*)(whh + (size_t)(gate*128 + r)*128);
        #pragma unroll
        for (int j = 0; j < 128; ++j) w[j] = wr[j];
    }
    __shared__ float h_lds[2][128];
    float c = 0.f;
    if (t < 128) h_lds[0][t] = 0.f;
    __syncthreads();
    const float* xpd = xp + (size_t)dir*(2048*512) + (size_t)b*(128*512);
    float xpv = xpd[(dir ? 127 : 0)*512 + t];
    for (int s = 0; s < 128; ++s) {
        const int ts = dir ? (127 - s) : s;
        // prefetch next step's xp so the global load overlaps the dot
        float xnext = 0.f;
        if (s < 127) {
            const int tsn = dir ? (126 - s) : (s + 1);
            xnext = xpd[tsn*512 + t];
        }
        const float* hb = h_lds[s & 1];
        float a0=0.f,a1=0.f,a2=0.f,a3=0.f;
        #pragma unroll
        for (int j = 0; j < 128; j += 4) {
            float4 h4 = *(const float4*)&hb[j];   // wave-uniform address -> LDS broadcast
            a0 = fmaf(w[j+0], h4.x, a0);
            a1 = fmaf(w[j+1], h4.y, a1);
            a2 = fmaf(w[j+2], h4.z, a2);
            a3 = fmaf(w[j+3], h4.w, a3);
        }
        float dot = xpv + ((a0+a1)+(a2+a3));
        // activated gate value (sig for i,f,o; tanh for g)
        float act = fmaf(mA, frcp(1.f + fexp2(kexp*dot)), mB);
        // quad broadcast: every lane of the quad gets all 4 activated gates
        float i_ = __shfl(act, qbase+0, 64);
        float f_ = __shfl(act, qbase+1, 64);
        float g_ = __shfl(act, qbase+2, 64);
        float o_ = __shfl(act, qbase+3, 64);
        c = f_*c + i_*g_;                  // redundant in all 4 lanes, consistent
        float h = o_ * tanh_(c);
        if (gate == 0) {
            h_lds[(s & 1) ^ 1][r] = h;
            hcat[((size_t)b*128 + ts)*256 + dir*128 + r] = h;
        }
        xpv = xnext;
        __syncthreads();
    }
}

// ------------- pairwise scorer: out[(i*128+j)*16+b] = S + sum_k w2_k / (ea_ik*eb_jk + 1) ----
__global__ __launch_bounds__(256) void pair_kernel(
    const float* __restrict__ ea, const float* __restrict__ eb,
    const float* __restrict__ w2, const float* __restrict__ Sp,
    float* __restrict__ out)
{
    __shared__ float eas[32][100];
    __shared__ float ebs[32][100];
    __shared__ float w2s[100];
    const int it = blockIdx.x * 32, jt = blockIdx.y * 32, b = blockIdx.z;
    const int tx = threadIdx.x;
    const float* eab = ea + (size_t)b*12800;
    const float* ebb = eb + (size_t)b*12800;
    for (int idx = tx; idx < 3200; idx += 256) {
        int r = idx / 100;
        int cc = idx - r*100;
        eas[r][cc] = eab[(it + r)*100 + cc];
        ebs[r][cc] = ebb[(jt + r)*100 + cc];
    }
    if (tx < 100) w2s[tx] = w2[tx];
    const float S = Sp[0];
    __syncthreads();
    const int jp = tx & 15, ip = tx >> 4;
    const int i0 = ip*2, j0 = jp*2;
    float acc00=S, acc01=S, acc10=S, acc11=S;
    #pragma unroll
    for (int k = 0; k < 100; k += 4) {
        float4 A0 = *(const float4*)&eas[i0][k];
        float4 A1 = *(const float4*)&eas[i0+1][k];
        float4 B0 = *(const float4*)&ebs[j0][k];
        float4 B1 = *(const float4*)&ebs[j0+1][k];
        float4 W  = *(const float4*)&w2s[k];
        acc00 = fmaf(W.x, frcp(fmaf(A0.x,B0.x,1.f)), acc00);
        acc01 = fmaf(W.x, frcp(fmaf(A0.x,B1.x,1.f)), acc01);
        acc10 = fmaf(W.x, frcp(fmaf(A1.x,B0.x,1.f)), acc10);
        acc11 = fmaf(W.x, frcp(fmaf(A1.x,B1.x,1.f)), acc11);
        acc00 = fmaf(W.y, frcp(fmaf(A0.y,B0.y,1.f)), acc00);
        acc01 = fmaf(W.y, frcp(fmaf(A0.y,B1.y,1.f)), acc01);
        acc10 = fmaf(W.y, frcp(fmaf(A1.y,B0.y,1.f)), acc10);
        acc11 = fmaf(W.y, frcp(fmaf(A1.y,B1.y,1.f)), acc11);
        acc00 = fmaf(W.z, frcp(fmaf(A0.z,B0.z,1.f)), acc00);
        acc01 = fmaf(W.z, frcp(fmaf(A0.z,B1.z,1.f)), acc01);
        acc10 = fmaf(W.z, frcp(fmaf(A1.z,B0.z,1.f)), acc10);
        acc11 = fmaf(W.z, frcp(fmaf(A1.z,B1.z,1.f)), acc11);
        acc00 = fmaf(W.w, frcp(fmaf(A0.w,B0.w,1.f)), acc00);
        acc01 = fmaf(W.w, frcp(fmaf(A0.w,B1.w,1.f)), acc01);
        acc10 = fmaf(W.w, frcp(fmaf(A1.w,B0.w,1.f)), acc10);
        acc11 = fmaf(W.w, frcp(fmaf(A1.w,B1.w,1.f)), acc11);
    }
    const int gi0 = it + i0, gj0 = jt + j0;
    out[((size_t)(gi0  )*128 + gj0  )*16 + b] = acc00;
    out[((size_t)(gi0  )*128 + gj0+1)*16 + b] = acc01;
    out[((size_t)(gi0+1)*128 + gj0  )*16 + b] = acc10;
    out[((size_t)(gi0+1)*128 + gj0+1)*16 + b] = acc11;
}

extern "C" void kernel_launch(void* const* d_in, const int* in_sizes, int n_in,
                              void* d_out, int out_size, void* d_ws, size_t ws_size,
                              hipStream_t stream)
{
    (void)in_sizes; (void)n_in; (void)out_size; (void)ws_size;
    const int*   widx = (const int*)d_in[0];
    const int*   pidx = (const int*)d_in[1];
    const float* wemb = (const float*)d_in[4];
    const float* temb = (const float*)d_in[5];
    const float* w_ih_l0f = (const float*)d_in[6];
    const float* w_hh_l0f = (const float*)d_in[7];
    const float* b_ih_l0f = (const float*)d_in[8];
    const float* b_hh_l0f = (const float*)d_in[9];
    const float* w_ih_l0b = (const float*)d_in[10];
    const float* w_hh_l0b = (const float*)d_in[11];
    const float* b_ih_l0b = (const float*)d_in[12];
    const float* b_hh_l0b = (const float*)d_in[13];
    const float* w_ih_l1f = (const float*)d_in[14];
    const float* w_hh_l1f = (const float*)d_in[15];
    const float* b_ih_l1f = (const float*)d_in[16];
    const float* b_hh_l1f = (const float*)d_in[17];
    const float* w_ih_l1b = (const float*)d_in[18];
    const float* w_hh_l1b = (const float*)d_in[19];
    const float* b_ih_l1b = (const float*)d_in[20];
    const float* b_hh_l1b = (const float*)d_in[21];
    const float* fc1_w = (const float*)d_in[22];
    const float* fc1_b = (const float*)d_in[23];
    const float* fc2_w = (const float*)d_in[24];
    const float* fc2_b = (const float*)d_in[25];

    float* ws  = (float*)d_ws;
    float* x   = ws;                  // 262144
    float* xp0 = x + 262144;          // 2 * 1048576
    float* h1  = xp0 + 2097152;       // 524288
    float* xp1 = h1 + 524288;         // 2 * 1048576
    float* h2  = xp1 + 2097152;       // 524288
    float* ea  = h2 + 524288;         // 204800
    float* eb  = ea + 204800;         // 204800
    float* w2  = eb + 204800;         // 128
    float* Sp  = w2 + 128;            // 1
    // total ~5.92M floats = 23.7 MB

    embed_kernel<<<1024, 256, 0, stream>>>(widx, pidx, wemb, temb, x);
    prep_kernel<<<1, 128, 0, stream>>>(fc2_w, fc2_b, w2, Sp);
    // layer 0 input projections (both dirs in grid.z), gate-permuted columns
    gemm_kernel<<<dim3(16,8,2), 256, 0, stream>>>(x, 128,
        w_ih_l0f, w_ih_l0b, 128,
        b_ih_l0f, b_hh_l0f, b_ih_l0b, b_hh_l0b,
        xp0, xp0 + 1048576, 512, 512, 0, 1);
    lstm_kernel<<<32, 512, 0, stream>>>(xp0, w_hh_l0f, w_hh_l0b, h1);
    // layer 1 input projections, gate-permuted columns
    gemm_kernel<<<dim3(16,8,2), 256, 0, stream>>>(h1, 256,
        w_ih_l1f, w_ih_l1b, 256,
        b_ih_l1f, b_hh_l1f, b_ih_l1b, b_hh_l1b,
        xp1, xp1 + 1048576, 512, 512, 0, 1);
    lstm_kernel<<<32, 512, 0, stream>>>(xp1, w_hh_l1f, w_hh_l1b, h2);
    // fc1: a = h2@wa^T -> ea = exp(2a); bp = h2@wb^T + fc1_b -> eb = exp(2bp)
    gemm_kernel<<<dim3(16,2,2), 256, 0, stream>>>(h2, 256,
        fc1_w, fc1_w + 256, 512,
        nullptr, nullptr, fc1_b, nullptr,
        ea, eb, 100, 100, 1, 0);
    pair_kernel<<<dim3(4,4,16), 256, 0, stream>>>(ea, eb, w2, Sp, (float*)d_out);
}

// Round 5
// 458.800 us; speedup vs baseline: 1.1242x; 1.1242x over previous
//
#include <hip/hip_runtime.h>

typedef float f4 __attribute__((ext_vector_type(4)));

__device__ __forceinline__ float frcp(float x){ return __builtin_amdgcn_rcpf(x); }
__device__ __forceinline__ float fexp2(float x){ return __builtin_amdgcn_exp2f(x); }
// sigmoid(x) = 1/(1+e^-x);  tanh(x) = 1 - 2/(e^{2x}+1)
__device__ __forceinline__ float sigf(float x){ return frcp(1.f + fexp2(-1.4426950408889634f*x)); }
__device__ __forceinline__ float tanh_(float x){ return 1.f - 2.f*frcp(1.f + fexp2(2.8853900817779268f*x)); }

// ---------------- embedding gather + concat -> x[b*128+t][128] fp32 ----------------
__global__ __launch_bounds__(256) void embed_kernel(
    const int* __restrict__ widx, const int* __restrict__ pidx,
    const float* __restrict__ wemb, const float* __restrict__ temb,
    float* __restrict__ x)
{
    int gid = blockIdx.x*256 + threadIdx.x;   // 262144 total
    int bt = gid >> 7, c = gid & 127;
    float v;
    if (c < 100) v = wemb[(size_t)widx[bt]*100 + c];
    else         v = temb[(size_t)pidx[bt]*28 + (c-100)];
    x[gid] = v;
}

// ---------------- w2[k] = -2*fc2_w[k]; S = sum(fc2_w) + fc2_b ----------------
__global__ void prep_kernel(const float* __restrict__ fc2w, const float* __restrict__ fc2b,
                            float* __restrict__ w2, float* __restrict__ Sp)
{
    __shared__ float red[128];
    int t = threadIdx.x;
    float w = (t < 100) ? fc2w[t] : 0.f;
    if (t < 100) w2[t] = -2.f*w;
    red[t] = w;
    __syncthreads();
    for (int s = 64; s > 0; s >>= 1) {
        if (t < s) red[t] += red[t+s];
        __syncthreads();
    }
    if (t == 0) Sp[0] = red[0] + fc2b[0];
}

// ---------------- generic C[m][n] = sum_k A[m][k]*B[n][k] (+biases) (opt exp(2x)) --------
// M fixed 2048 (grid.x=16, BM=128). grid.z selects B/bias/C set. BN=64, BK=16.
// permflag: output column p holds gate-row gr(p) = (p&3)*128 + (p>>2) (for LSTM layout).
__global__ __launch_bounds__(256) void gemm_kernel(
    const float* __restrict__ A, int K,
    const float* __restrict__ B0, const float* __restrict__ B1, int ldb,
    const float* __restrict__ bias0a, const float* __restrict__ bias0b,
    const float* __restrict__ bias1a, const float* __restrict__ bias1b,
    float* __restrict__ C0, float* __restrict__ C1, int ldc, int N,
    int expflag, int permflag)
{
    __shared__ float As[16][132];   // [k][m], pad 132 (16B-aligned rows)
    __shared__ float Bs[16][68];    // [k][n]
    const int z = blockIdx.z;
    const float* B  = z ? B1 : B0;
    const float* ba = z ? bias1a : bias0a;
    const float* bb = z ? bias1b : bias0b;
    float* C = z ? C1 : C0;
    const int m0 = blockIdx.x * 128;
    const int n0 = blockIdx.y * 64;
    const int tx = threadIdx.x;
    const int tm = tx & 15, tn = tx >> 4;       // 8x4 micro-tile
    const int arow = tx >> 1, akq = (tx & 1) * 8;
    const int brow = tx >> 2, bkq = (tx & 3) * 4;
    float acc[8][4];
    #pragma unroll
    for (int r=0;r<8;++r){
        #pragma unroll
        for (int c=0;c<4;++c) acc[r][c]=0.f; }
    const int bn = n0 + brow;
    const int brow_src = permflag ? ((bn & 3)*128 + (bn >> 2)) : bn;
    for (int k0 = 0; k0 < K; k0 += 16) {
        const float* ap = A + (size_t)(m0+arow)*K + k0 + akq;
        float4 a0 = *(const float4*)ap;
        float4 a1 = *(const float4*)(ap+4);
        float4 bv = make_float4(0.f,0.f,0.f,0.f);
        if (bn < N) {
            const float* bp = B + (size_t)brow_src*ldb + k0 + bkq;
            bv = *(const float4*)bp;
        }
        __syncthreads();
        As[akq+0][arow]=a0.x; As[akq+1][arow]=a0.y; As[akq+2][arow]=a0.z; As[akq+3][arow]=a0.w;
        As[akq+4][arow]=a1.x; As[akq+5][arow]=a1.y; As[akq+6][arow]=a1.z; As[akq+7][arow]=a1.w;
        Bs[bkq+0][brow]=bv.x; Bs[bkq+1][brow]=bv.y; Bs[bkq+2][brow]=bv.z; Bs[bkq+3][brow]=bv.w;
        __syncthreads();
        #pragma unroll
        for (int kk = 0; kk < 16; ++kk) {
            float4 av0 = *(const float4*)&As[kk][tm*8];
            float4 av1 = *(const float4*)&As[kk][tm*8+4];
            float4 bvv = *(const float4*)&Bs[kk][tn*4];
            float a[8] = {av0.x,av0.y,av0.z,av0.w,av1.x,av1.y,av1.z,av1.w};
            float b[4] = {bvv.x,bvv.y,bvv.z,bvv.w};
            #pragma unroll
            for (int r=0;r<8;++r){
                #pragma unroll
                for (int c=0;c<4;++c)
                    acc[r][c] = fmaf(a[r], b[c], acc[r][c]);
            }
        }
    }
    float bias[4];
    #pragma unroll
    for (int c=0;c<4;++c) {
        int n = n0 + tn*4 + c;
        int nsrc = permflag ? ((n & 3)*128 + (n >> 2)) : n;
        float v = 0.f;
        if (n < N) {
            if (ba) v += ba[nsrc];
            if (bb) v += bb[nsrc];
        }
        bias[c] = v;
    }
    #pragma unroll
    for (int r=0;r<8;++r) {
        int m = m0 + tm*8 + r;
        float v[4];
        #pragma unroll
        for (int c=0;c<4;++c) {
            float t = acc[r][c] + bias[c];
            if (expflag) t = fexp2(fminf(fmaxf(t,-40.f),40.f)*2.8853900817779268f); // e^{2t}
            v[c] = t;
        }
        int n = n0 + tn*4;
        if (n + 3 < N) {
            float4 st; st.x=v[0]; st.y=v[1]; st.z=v[2]; st.w=v[3];
            *(float4*)&C[(size_t)m*ldc + n] = st;
        } else {
            #pragma unroll
            for (int c=0;c<4;++c) if (n+c < N) C[(size_t)m*ldc + n + c] = v[c];
        }
    }
}

// ---------------- LSTM: one block per (b, dir); gate-interleaved thread map ----------------
// thread t: row r = t>>2, gate g = t&3 (i,f,g,o). Weight row gr = g*128 + r pinned in VGPRs
// via asm-volatile global_load_dwordx4 outputs (cannot be deleted/remat'ed; rounds 2-4 showed
// plain and volatile C++ loads end up reloaded or scratch-spilled, VGPR_Count stuck at 100).
// xp comes in pre-permuted (col p = gate row gr(p)). One barrier per step; h double-buffered.
__global__ __launch_bounds__(512)
__attribute__((amdgpu_waves_per_eu(2,2)))
void lstm_kernel(
    const float* __restrict__ xp,      // [dir][2048][512] permuted cols
    const float* __restrict__ whh_f, const float* __restrict__ whh_b,
    float* __restrict__ hcat)          // [16][128][256]
{
    const int b = blockIdx.x & 15;
    const int dir = blockIdx.x >> 4;
    const int t = threadIdx.x;
    const int gate = t & 3, r = t >> 2;
    const int lane = t & 63, qbase = lane & ~3;
    const float* whh = dir ? whh_b : whh_f;
    // per-lane activation constants: sig(x)=1/(1+2^(-x*log2e)); tanh(x)=1-2/(1+2^(2x*log2e))
    const float kexp = (gate == 2) ? 2.8853900817779268f : -1.4426950408889634f;
    const float mA   = (gate == 2) ? -2.f : 1.f;
    const float mB   = (gate == 2) ?  1.f : 0.f;

    const float* wp = whh + (size_t)(gate*128 + r)*128;
    f4 W00,W01,W02,W03,W04,W05,W06,W07,W08,W09,W10,W11,W12,W13,W14,W15,
       W16,W17,W18,W19,W20,W21,W22,W23,W24,W25,W26,W27,W28,W29,W30,W31;
#define LDW(reg, offs) asm volatile("global_load_dwordx4 %0, %1, off offset:" offs \
                                    : "=v"(reg) : "v"(wp))
    LDW(W00,"0");   LDW(W01,"16");  LDW(W02,"32");  LDW(W03,"48");
    LDW(W04,"64");  LDW(W05,"80");  LDW(W06,"96");  LDW(W07,"112");
    LDW(W08,"128"); LDW(W09,"144"); LDW(W10,"160"); LDW(W11,"176");
    LDW(W12,"192"); LDW(W13,"208"); LDW(W14,"224"); LDW(W15,"240");
    LDW(W16,"256"); LDW(W17,"272"); LDW(W18,"288"); LDW(W19,"304");
    LDW(W20,"320"); LDW(W21,"336"); LDW(W22,"352"); LDW(W23,"368");
    LDW(W24,"384"); LDW(W25,"400"); LDW(W26,"416"); LDW(W27,"432");
    LDW(W28,"448"); LDW(W29,"464"); LDW(W30,"480"); LDW(W31,"496");
#undef LDW
    asm volatile("s_waitcnt vmcnt(0)" ::: "memory");

    __shared__ float h_lds[2][128];
    float c = 0.f;
    if (t < 128) h_lds[0][t] = 0.f;
    __syncthreads();
    const float* xpd = xp + (size_t)dir*(2048*512) + (size_t)b*(128*512);
    float xpv = xpd[(dir ? 127 : 0)*512 + t];
    for (int s = 0; s < 128; ++s) {
        const int ts = dir ? (127 - s) : s;
        // branchless prefetch of next step's xp (clamped; last-iter load is harmless)
        const int tsn = dir ? (126 - s < 0 ? 0 : 126 - s) : (s + 1 > 127 ? 127 : s + 1);
        float xnext = xpd[tsn*512 + t];
        const float* hb = h_lds[s & 1];
        float a0=0.f,a1=0.f,a2=0.f,a3=0.f;
#define FMA4(Wv, j) { float4 h4 = *(const float4*)&hb[j]; \
        a0 = fmaf(Wv.x, h4.x, a0); a1 = fmaf(Wv.y, h4.y, a1); \
        a2 = fmaf(Wv.z, h4.z, a2); a3 = fmaf(Wv.w, h4.w, a3); }
        FMA4(W00,0)   FMA4(W01,4)   FMA4(W02,8)   FMA4(W03,12)
        FMA4(W04,16)  FMA4(W05,20)  FMA4(W06,24)  FMA4(W07,28)
        FMA4(W08,32)  FMA4(W09,36)  FMA4(W10,40)  FMA4(W11,44)
        FMA4(W12,48)  FMA4(W13,52)  FMA4(W14,56)  FMA4(W15,60)
        FMA4(W16,64)  FMA4(W17,68)  FMA4(W18,72)  FMA4(W19,76)
        FMA4(W20,80)  FMA4(W21,84)  FMA4(W22,88)  FMA4(W23,92)
        FMA4(W24,96)  FMA4(W25,100) FMA4(W26,104) FMA4(W27,108)
        FMA4(W28,112) FMA4(W29,116) FMA4(W30,120) FMA4(W31,124)
#undef FMA4
        float dot = xpv + ((a0+a1)+(a2+a3));
        // activated gate value (sig for i,f,o; tanh for g)
        float act = fmaf(mA, frcp(1.f + fexp2(kexp*dot)), mB);
        // quad broadcast: every lane of the quad gets all 4 activated gates
        float i_ = __shfl(act, qbase+0, 64);
        float f_ = __shfl(act, qbase+1, 64);
        float g_ = __shfl(act, qbase+2, 64);
        float o_ = __shfl(act, qbase+3, 64);
        c = f_*c + i_*g_;                  // redundant in all 4 lanes, consistent
        float h = o_ * tanh_(c);
        if (gate == 0) {
            h_lds[(s & 1) ^ 1][r] = h;
            hcat[((size_t)b*128 + ts)*256 + dir*128 + r] = h;
        }
        xpv = xnext;
        __syncthreads();
    }
}

// ------------- pairwise scorer: out[(i*128+j)*16+b] = S + sum_k w2_k / (ea_ik*eb_jk + 1) ----
__global__ __launch_bounds__(256) void pair_kernel(
    const float* __restrict__ ea, const float* __restrict__ eb,
    const float* __restrict__ w2, const float* __restrict__ Sp,
    float* __restrict__ out)
{
    __shared__ float eas[32][100];
    __shared__ float ebs[32][100];
    __shared__ float w2s[100];
    const int it = blockIdx.x * 32, jt = blockIdx.y * 32, b = blockIdx.z;
    const int tx = threadIdx.x;
    const float* eab = ea + (size_t)b*12800;
    const float* ebb = eb + (size_t)b*12800;
    for (int idx = tx; idx < 3200; idx += 256) {
        int r = idx / 100;
        int cc = idx - r*100;
        eas[r][cc] = eab[(it + r)*100 + cc];
        ebs[r][cc] = ebb[(jt + r)*100 + cc];
    }
    if (tx < 100) w2s[tx] = w2[tx];
    const float S = Sp[0];
    __syncthreads();
    const int jp = tx & 15, ip = tx >> 4;
    const int i0 = ip*2, j0 = jp*2;
    float acc00=S, acc01=S, acc10=S, acc11=S;
    #pragma unroll
    for (int k = 0; k < 100; k += 4) {
        float4 A0 = *(const float4*)&eas[i0][k];
        float4 A1 = *(const float4*)&eas[i0+1][k];
        float4 B0 = *(const float4*)&ebs[j0][k];
        float4 B1 = *(const float4*)&ebs[j0+1][k];
        float4 W  = *(const float4*)&w2s[k];
        acc00 = fmaf(W.x, frcp(fmaf(A0.x,B0.x,1.f)), acc00);
        acc01 = fmaf(W.x, frcp(fmaf(A0.x,B1.x,1.f)), acc01);
        acc10 = fmaf(W.x, frcp(fmaf(A1.x,B0.x,1.f)), acc10);
        acc11 = fmaf(W.x, frcp(fmaf(A1.x,B1.x,1.f)), acc11);
        acc00 = fmaf(W.y, frcp(fmaf(A0.y,B0.y,1.f)), acc00);
        acc01 = fmaf(W.y, frcp(fmaf(A0.y,B1.y,1.f)), acc01);
        acc10 = fmaf(W.y, frcp(fmaf(A1.y,B0.y,1.f)), acc10);
        acc11 = fmaf(W.y, frcp(fmaf(A1.y,B1.y,1.f)), acc11);
        acc00 = fmaf(W.z, frcp(fmaf(A0.z,B0.z,1.f)), acc00);
        acc01 = fmaf(W.z, frcp(fmaf(A0.z,B1.z,1.f)), acc01);
        acc10 = fmaf(W.z, frcp(fmaf(A1.z,B0.z,1.f)), acc10);
        acc11 = fmaf(W.z, frcp(fmaf(A1.z,B1.z,1.f)), acc11);
        acc00 = fmaf(W.w, frcp(fmaf(A0.w,B0.w,1.f)), acc00);
        acc01 = fmaf(W.w, frcp(fmaf(A0.w,B1.w,1.f)), acc01);
        acc10 = fmaf(W.w, frcp(fmaf(A1.w,B0.w,1.f)), acc10);
        acc11 = fmaf(W.w, frcp(fmaf(A1.w,B1.w,1.f)), acc11);
    }
    const int gi0 = it + i0, gj0 = jt + j0;
    out[((size_t)(gi0  )*128 + gj0  )*16 + b] = acc00;
    out[((size_t)(gi0  )*128 + gj0+1)*16 + b] = acc01;
    out[((size_t)(gi0+1)*128 + gj0  )*16 + b] = acc10;
    out[((size_t)(gi0+1)*128 + gj0+1)*16 + b] = acc11;
}

extern "C" void kernel_launch(void* const* d_in, const int* in_sizes, int n_in,
                              void* d_out, int out_size, void* d_ws, size_t ws_size,
                              hipStream_t stream)
{
    (void)in_sizes; (void)n_in; (void)out_size; (void)ws_size;
    const int*   widx = (const int*)d_in[0];
    const int*   pidx = (const int*)d_in[1];
    const float* wemb = (const float*)d_in[4];
    const float* temb = (const float*)d_in[5];
    const float* w_ih_l0f = (const float*)d_in[6];
    const float* w_hh_l0f = (const float*)d_in[7];
    const float* b_ih_l0f = (const float*)d_in[8];
    const float* b_hh_l0f = (const float*)d_in[9];
    const float* w_ih_l0b = (const float*)d_in[10];
    const float* w_hh_l0b = (const float*)d_in[11];
    const float* b_ih_l0b = (const float*)d_in[12];
    const float* b_hh_l0b = (const float*)d_in[13];
    const float* w_ih_l1f = (const float*)d_in[14];
    const float* w_hh_l1f = (const float*)d_in[15];
    const float* b_ih_l1f = (const float*)d_in[16];
    const float* b_hh_l1f = (const float*)d_in[17];
    const float* w_ih_l1b = (const float*)d_in[18];
    const float* w_hh_l1b = (const float*)d_in[19];
    const float* b_ih_l1b = (const float*)d_in[20];
    const float* b_hh_l1b = (const float*)d_in[21];
    const float* fc1_w = (const float*)d_in[22];
    const float* fc1_b = (const float*)d_in[23];
    const float* fc2_w = (const float*)d_in[24];
    const float* fc2_b = (const float*)d_in[25];

    float* ws  = (float*)d_ws;
    float* x   = ws;                  // 262144
    float* xp0 = x + 262144;          // 2 * 1048576
    float* h1  = xp0 + 2097152;       // 524288
    float* xp1 = h1 + 524288;         // 2 * 1048576
    float* h2  = xp1 + 2097152;       // 524288
    float* ea  = h2 + 524288;         // 204800
    float* eb  = ea + 204800;         // 204800
    float* w2  = eb + 204800;         // 128
    float* Sp  = w2 + 128;            // 1
    // total ~5.92M floats = 23.7 MB

    embed_kernel<<<1024, 256, 0, stream>>>(widx, pidx, wemb, temb, x);
    prep_kernel<<<1, 128, 0, stream>>>(fc2_w, fc2_b, w2, Sp);
    // layer 0 input projections (both dirs in grid.z), gate-permuted columns
    gemm_kernel<<<dim3(16,8,2), 256, 0, stream>>>(x, 128,
        w_ih_l0f, w_ih_l0b, 128,
        b_ih_l0f, b_hh_l0f, b_ih_l0b, b_hh_l0b,
        xp0, xp0 + 1048576, 512, 512, 0, 1);
    lstm_kernel<<<32, 512, 0, stream>>>(xp0, w_hh_l0f, w_hh_l0b, h1);
    // layer 1 input projections, gate-permuted columns
    gemm_kernel<<<dim3(16,8,2), 256, 0, stream>>>(h1, 256,
        w_ih_l1f, w_ih_l1b, 256,
        b_ih_l1f, b_hh_l1f, b_ih_l1b, b_hh_l1b,
        xp1, xp1 + 1048576, 512, 512, 0, 1);
    lstm_kernel<<<32, 512, 0, stream>>>(xp1, w_hh_l1f, w_hh_l1b, h2);
    // fc1: a = h2@wa^T -> ea = exp(2a); bp = h2@wb^T + fc1_b -> eb = exp(2bp)
    gemm_kernel<<<dim3(16,2,2), 256, 0, stream>>>(h2, 256,
        fc1_w, fc1_w + 256, 512,
        nullptr, nullptr, fc1_b, nullptr,
        ea, eb, 100, 100, 1, 0);
    pair_kernel<<<dim3(4,4,16), 256, 0, stream>>>(ea, eb, w2, Sp, (float*)d_out);
}

// Round 6
// 397.275 us; speedup vs baseline: 1.2983x; 1.1549x over previous
//
#include <hip/hip_runtime.h>

typedef float v2f __attribute__((ext_vector_type(2)));

__device__ __forceinline__ float frcp(float x){ return __builtin_amdgcn_rcpf(x); }
__device__ __forceinline__ float fexp2(float x){ return __builtin_amdgcn_exp2f(x); }
// sigmoid(x) = 1/(1+e^-x);  tanh(x) = 1 - 2/(e^{2x}+1)
__device__ __forceinline__ float sigf(float x){ return frcp(1.f + fexp2(-1.4426950408889634f*x)); }
__device__ __forceinline__ float tanh_(float x){ return 1.f - 2.f*frcp(1.f + fexp2(2.8853900817779268f*x)); }

// ---------------- embedding gather + concat -> x[b*128+t][128] fp32 ----------------
__global__ __launch_bounds__(256) void embed_kernel(
    const int* __restrict__ widx, const int* __restrict__ pidx,
    const float* __restrict__ wemb, const float* __restrict__ temb,
    float* __restrict__ x)
{
    int gid = blockIdx.x*256 + threadIdx.x;   // 262144 total
    int bt = gid >> 7, c = gid & 127;
    float v;
    if (c < 100) v = wemb[(size_t)widx[bt]*100 + c];
    else         v = temb[(size_t)pidx[bt]*28 + (c-100)];
    x[gid] = v;
}

// ---------------- generic C[m][n] = sum_k A[m][k]*B[n][k] (+biases) (opt exp(2x)) --------
// M fixed 2048 (grid.x=16, BM=128). grid.z selects B/bias/C set. BN=64, BK=16.
// permflag: output column p holds gate-row gr(p) = (p&3)*128 + (p>>2) (for LSTM layout).
__global__ __launch_bounds__(256) void gemm_kernel(
    const float* __restrict__ A, int K,
    const float* __restrict__ B0, const float* __restrict__ B1, int ldb,
    const float* __restrict__ bias0a, const float* __restrict__ bias0b,
    const float* __restrict__ bias1a, const float* __restrict__ bias1b,
    float* __restrict__ C0, float* __restrict__ C1, int ldc, int N,
    int expflag, int permflag)
{
    __shared__ float As[16][132];   // [k][m], pad 132 (16B-aligned rows)
    __shared__ float Bs[16][68];    // [k][n]
    const int z = blockIdx.z;
    const float* B  = z ? B1 : B0;
    const float* ba = z ? bias1a : bias0a;
    const float* bb = z ? bias1b : bias0b;
    float* C = z ? C1 : C0;
    const int m0 = blockIdx.x * 128;
    const int n0 = blockIdx.y * 64;
    const int tx = threadIdx.x;
    const int tm = tx & 15, tn = tx >> 4;       // 8x4 micro-tile
    const int arow = tx >> 1, akq = (tx & 1) * 8;
    const int brow = tx >> 2, bkq = (tx & 3) * 4;
    float acc[8][4];
    #pragma unroll
    for (int r=0;r<8;++r){
        #pragma unroll
        for (int c=0;c<4;++c) acc[r][c]=0.f; }
    const int bn = n0 + brow;
    const int brow_src = permflag ? ((bn & 3)*128 + (bn >> 2)) : bn;
    for (int k0 = 0; k0 < K; k0 += 16) {
        const float* ap = A + (size_t)(m0+arow)*K + k0 + akq;
        float4 a0 = *(const float4*)ap;
        float4 a1 = *(const float4*)(ap+4);
        float4 bv = make_float4(0.f,0.f,0.f,0.f);
        if (bn < N) {
            const float* bp = B + (size_t)brow_src*ldb + k0 + bkq;
            bv = *(const float4*)bp;
        }
        __syncthreads();
        As[akq+0][arow]=a0.x; As[akq+1][arow]=a0.y; As[akq+2][arow]=a0.z; As[akq+3][arow]=a0.w;
        As[akq+4][arow]=a1.x; As[akq+5][arow]=a1.y; As[akq+6][arow]=a1.z; As[akq+7][arow]=a1.w;
        Bs[bkq+0][brow]=bv.x; Bs[bkq+1][brow]=bv.y; Bs[bkq+2][brow]=bv.z; Bs[bkq+3][brow]=bv.w;
        __syncthreads();
        #pragma unroll
        for (int kk = 0; kk < 16; ++kk) {
            float4 av0 = *(const float4*)&As[kk][tm*8];
            float4 av1 = *(const float4*)&As[kk][tm*8+4];
            float4 bvv = *(const float4*)&Bs[kk][tn*4];
            float a[8] = {av0.x,av0.y,av0.z,av0.w,av1.x,av1.y,av1.z,av1.w};
            float b[4] = {bvv.x,bvv.y,bvv.z,bvv.w};
            #pragma unroll
            for (int r=0;r<8;++r){
                #pragma unroll
                for (int c=0;c<4;++c)
                    acc[r][c] = fmaf(a[r], b[c], acc[r][c]);
            }
        }
    }
    float bias[4];
    #pragma unroll
    for (int c=0;c<4;++c) {
        int n = n0 + tn*4 + c;
        int nsrc = permflag ? ((n & 3)*128 + (n >> 2)) : n;
        float v = 0.f;
        if (n < N) {
            if (ba) v += ba[nsrc];
            if (bb) v += bb[nsrc];
        }
        bias[c] = v;
    }
    #pragma unroll
    for (int r=0;r<8;++r) {
        int m = m0 + tm*8 + r;
        float v[4];
        #pragma unroll
        for (int c=0;c<4;++c) {
            float t = acc[r][c] + bias[c];
            if (expflag) t = fexp2(fminf(fmaxf(t,-40.f),40.f)*2.8853900817779268f); // e^{2t}
            v[c] = t;
        }
        int n = n0 + tn*4;
        if (n + 3 < N) {
            float4 st; st.x=v[0]; st.y=v[1]; st.z=v[2]; st.w=v[3];
            *(float4*)&C[(size_t)m*ldc + n] = st;
        } else {
            #pragma unroll
            for (int c=0;c<4;++c) if (n+c < N) C[(size_t)m*ldc + n + c] = v[c];
        }
    }
}

// ---------------- LSTM: one block per (b, dir) -------------------------------------------
// Thread t: half = t&1 (k-range [64*half,64*half+64)), p = t>>1, gate = p&3, rp = p>>2.
// Thread covers TWO gate-rows (gate*128 + 2rp, +1) over its k-half: the h4 LDS broadcast
// read is reused for both rows (halves LDS instrs vs 1-row/thread), and the row pair packs
// into float2 -> v_pk_fma_f32 (halves VALU issue). w = 64 x float2 = 128 VGPRs.
// __launch_bounds__(512,2): min 2 waves/EU -> 256-VGPR cap (rounds 2-5: allocator refused
// >~104 under default target, spilling/reloading w each step).
// Combine: k-halves via shfl_xor(1); gates via shfl in 8-lane group; 1 barrier/step.
__global__ __launch_bounds__(512, 2)
void lstm_kernel(
    const float* __restrict__ xp,      // [dir][2048][512] permuted cols (col 4r+g <- gate row g*128+r)
    const float* __restrict__ whh_f, const float* __restrict__ whh_b,
    float* __restrict__ hcat)          // [16][128][256]
{
    const int b = blockIdx.x & 15;
    const int dir = blockIdx.x >> 4;
    const int t = threadIdx.x;
    const int half = t & 1;
    const int p = t >> 1;
    const int gate = p & 3, rp = p >> 2;      // rows r0=2rp, r1=2rp+1
    const int lane = t & 63, gbase = lane & ~7;
    const float* whh = dir ? whh_b : whh_f;
    // activation constants: sig(x)=1/(1+2^(-x*log2e)); tanh(x)=1-2/(1+2^(2x*log2e))
    const float kexp = (gate == 2) ? 2.8853900817779268f : -1.4426950408889634f;
    const float mA   = (gate == 2) ? -2.f : 1.f;
    const float mB   = (gate == 2) ?  1.f : 0.f;

    // load w: rows gr0=gate*128+2rp and gr0+1, k in [64*half, 64*half+64), packed (row0,row1)
    v2f w[64];
    {
        const float* wr = whh + (size_t)(gate*128 + 2*rp)*128 + 64*half;
        #pragma unroll
        for (int j = 0; j < 64; j += 4) {
            float4 a = *(const float4*)(wr + j);
            float4 bq = *(const float4*)(wr + 128 + j);
            w[j+0] = (v2f){a.x, bq.x};
            w[j+1] = (v2f){a.y, bq.y};
            w[j+2] = (v2f){a.z, bq.z};
            w[j+3] = (v2f){a.w, bq.w};
        }
    }

    __shared__ float h_lds[2][128];
    float c = 0.f;
    if (t < 128) h_lds[0][t] = 0.f;
    __syncthreads();
    const float* xpd = xp + (size_t)dir*(2048*512) + (size_t)b*(128*512);
    // this thread's own row and xp column (permuted layout: col = 4*row + gate)
    const int myrow = 2*rp + half;
    const int mycol = 4*myrow + gate;
    float xpv = xpd[(dir ? 127 : 0)*512 + mycol];
    const int koff = 64*half;
    for (int s = 0; s < 128; ++s) {
        const int ts = dir ? (127 - s) : s;
        // branchless prefetch of next step's xp (clamped; last-iter load is harmless)
        const int tsn = dir ? (126 - s < 0 ? 0 : 126 - s) : (s + 1 > 127 ? 127 : s + 1);
        float xnext = xpd[tsn*512 + mycol];
        const float* hb = &h_lds[s & 1][koff];
        v2f da = (v2f){0.f,0.f}, db = (v2f){0.f,0.f};
        #pragma unroll
        for (int j = 0; j < 64; j += 4) {
            float4 h4 = *(const float4*)&hb[j];     // 2-addr broadcast (free)
            da += w[j+0] * (v2f){h4.x, h4.x};
            db += w[j+1] * (v2f){h4.y, h4.y};
            da += w[j+2] * (v2f){h4.z, h4.z};
            db += w[j+3] * (v2f){h4.w, h4.w};
        }
        v2f d = da + db;                            // (row0 partial, row1 partial) over k-half
        float d0 = d.x + __shfl_xor(d.x, 1, 64);    // full dots (both halves have them)
        float d1 = d.y + __shfl_xor(d.y, 1, 64);
        float dot = xpv + (half ? d1 : d0);
        float act = fmaf(mA, frcp(1.f + fexp2(kexp*dot)), mB);
        // gate combine: row (2rp+half)'s gate g sits at lane gbase + 2g + half
        float i_ = __shfl(act, gbase + 0 + half, 64);
        float f_ = __shfl(act, gbase + 2 + half, 64);
        float g_ = __shfl(act, gbase + 4 + half, 64);
        float o_ = __shfl(act, gbase + 6 + half, 64);
        c = f_*c + i_*g_;                           // redundant across the 4 gate-lanes of this row
        float h = o_ * tanh_(c);
        if ((lane & 7) < 2) {                        // lane gbase+0 -> row 2rp, gbase+1 -> row 2rp+1
            h_lds[(s & 1) ^ 1][myrow] = h;
            hcat[((size_t)b*128 + ts)*256 + dir*128 + myrow] = h;
        }
        xpv = xnext;
        __syncthreads();
    }
}

// ------------- pairwise scorer: out[(i*128+j)*16+b] = S + sum_k w2_k / (ea_ik*eb_jk + 1) ----
// w2[k] = -2*fc2_w[k], S = sum(fc2_w)+fc2_b computed in-block (prep fused).
__global__ __launch_bounds__(256) void pair_kernel(
    const float* __restrict__ ea, const float* __restrict__ eb,
    const float* __restrict__ fc2w, const float* __restrict__ fc2b,
    float* __restrict__ out)
{
    __shared__ float eas[32][100];
    __shared__ float ebs[32][100];
    __shared__ float w2s[100];
    __shared__ float red[128];
    const int it = blockIdx.x * 32, jt = blockIdx.y * 32, b = blockIdx.z;
    const int tx = threadIdx.x;
    const float* eab = ea + (size_t)b*12800;
    const float* ebb = eb + (size_t)b*12800;
    for (int idx = tx; idx < 3200; idx += 256) {
        int r = idx / 100;
        int cc = idx - r*100;
        eas[r][cc] = eab[(it + r)*100 + cc];
        ebs[r][cc] = ebb[(jt + r)*100 + cc];
    }
    if (tx < 128) {
        float wv = (tx < 100) ? fc2w[tx] : 0.f;
        if (tx < 100) w2s[tx] = -2.f*wv;
        red[tx] = wv;
    }
    __syncthreads();
    for (int s2 = 64; s2 > 0; s2 >>= 1) {
        if (tx < s2) red[tx] += red[tx+s2];
        __syncthreads();
    }
    const float S = red[0] + fc2b[0];
    const int jp = tx & 15, ip = tx >> 4;
    const int i0 = ip*2, j0 = jp*2;
    float acc00=S, acc01=S, acc10=S, acc11=S;
    #pragma unroll
    for (int k = 0; k < 100; k += 4) {
        float4 A0 = *(const float4*)&eas[i0][k];
        float4 A1 = *(const float4*)&eas[i0+1][k];
        float4 B0 = *(const float4*)&ebs[j0][k];
        float4 B1 = *(const float4*)&ebs[j0+1][k];
        float4 W  = *(const float4*)&w2s[k];
        acc00 = fmaf(W.x, frcp(fmaf(A0.x,B0.x,1.f)), acc00);
        acc01 = fmaf(W.x, frcp(fmaf(A0.x,B1.x,1.f)), acc01);
        acc10 = fmaf(W.x, frcp(fmaf(A1.x,B0.x,1.f)), acc10);
        acc11 = fmaf(W.x, frcp(fmaf(A1.x,B1.x,1.f)), acc11);
        acc00 = fmaf(W.y, frcp(fmaf(A0.y,B0.y,1.f)), acc00);
        acc01 = fmaf(W.y, frcp(fmaf(A0.y,B1.y,1.f)), acc01);
        acc10 = fmaf(W.y, frcp(fmaf(A1.y,B0.y,1.f)), acc10);
        acc11 = fmaf(W.y, frcp(fmaf(A1.y,B1.y,1.f)), acc11);
        acc00 = fmaf(W.z, frcp(fmaf(A0.z,B0.z,1.f)), acc00);
        acc01 = fmaf(W.z, frcp(fmaf(A0.z,B1.z,1.f)), acc01);
        acc10 = fmaf(W.z, frcp(fmaf(A1.z,B0.z,1.f)), acc10);
        acc11 = fmaf(W.z, frcp(fmaf(A1.z,B1.z,1.f)), acc11);
        acc00 = fmaf(W.w, frcp(fmaf(A0.w,B0.w,1.f)), acc00);
        acc01 = fmaf(W.w, frcp(fmaf(A0.w,B1.w,1.f)), acc01);
        acc10 = fmaf(W.w, frcp(fmaf(A1.w,B0.w,1.f)), acc10);
        acc11 = fmaf(W.w, frcp(fmaf(A1.w,B1.w,1.f)), acc11);
    }
    const int gi0 = it + i0, gj0 = jt + j0;
    out[((size_t)(gi0  )*128 + gj0  )*16 + b] = acc00;
    out[((size_t)(gi0  )*128 + gj0+1)*16 + b] = acc01;
    out[((size_t)(gi0+1)*128 + gj0  )*16 + b] = acc10;
    out[((size_t)(gi0+1)*128 + gj0+1)*16 + b] = acc11;
}

extern "C" void kernel_launch(void* const* d_in, const int* in_sizes, int n_in,
                              void* d_out, int out_size, void* d_ws, size_t ws_size,
                              hipStream_t stream)
{
    (void)in_sizes; (void)n_in; (void)out_size; (void)ws_size;
    const int*   widx = (const int*)d_in[0];
    const int*   pidx = (const int*)d_in[1];
    const float* wemb = (const float*)d_in[4];
    const float* temb = (const float*)d_in[5];
    const float* w_ih_l0f = (const float*)d_in[6];
    const float* w_hh_l0f = (const float*)d_in[7];
    const float* b_ih_l0f = (const float*)d_in[8];
    const float* b_hh_l0f = (const float*)d_in[9];
    const float* w_ih_l0b = (const float*)d_in[10];
    const float* w_hh_l0b = (const float*)d_in[11];
    const float* b_ih_l0b = (const float*)d_in[12];
    const float* b_hh_l0b = (const float*)d_in[13];
    const float* w_ih_l1f = (const float*)d_in[14];
    const float* w_hh_l1f = (const float*)d_in[15];
    const float* b_ih_l1f = (const float*)d_in[16];
    const float* b_hh_l1f = (const float*)d_in[17];
    const float* w_ih_l1b = (const float*)d_in[18];
    const float* w_hh_l1b = (const float*)d_in[19];
    const float* b_ih_l1b = (const float*)d_in[20];
    const float* b_hh_l1b = (const float*)d_in[21];
    const float* fc1_w = (const float*)d_in[22];
    const float* fc1_b = (const float*)d_in[23];
    const float* fc2_w = (const float*)d_in[24];
    const float* fc2_b = (const float*)d_in[25];

    float* ws  = (float*)d_ws;
    float* x   = ws;                  // 262144
    float* xp0 = x + 262144;          // 2 * 1048576
    float* h1  = xp0 + 2097152;       // 524288
    float* xp1 = h1 + 524288;         // 2 * 1048576
    float* h2  = xp1 + 2097152;       // 524288
    float* ea  = h2 + 524288;         // 204800
    float* eb  = ea + 204800;         // 204800
    // total ~5.92M floats = 23.7 MB

    embed_kernel<<<1024, 256, 0, stream>>>(widx, pidx, wemb, temb, x);
    // layer 0 input projections (both dirs in grid.z), gate-permuted columns
    gemm_kernel<<<dim3(16,8,2), 256, 0, stream>>>(x, 128,
        w_ih_l0f, w_ih_l0b, 128,
        b_ih_l0f, b_hh_l0f, b_ih_l0b, b_hh_l0b,
        xp0, xp0 + 1048576, 512, 512, 0, 1);
    lstm_kernel<<<32, 512, 0, stream>>>(xp0, w_hh_l0f, w_hh_l0b, h1);
    // layer 1 input projections, gate-permuted columns
    gemm_kernel<<<dim3(16,8,2), 256, 0, stream>>>(h1, 256,
        w_ih_l1f, w_ih_l1b, 256,
        b_ih_l1f, b_hh_l1f, b_ih_l1b, b_hh_l1b,
        xp1, xp1 + 1048576, 512, 512, 0, 1);
    lstm_kernel<<<32, 512, 0, stream>>>(xp1, w_hh_l1f, w_hh_l1b, h2);
    // fc1: a = h2@wa^T -> ea = exp(2a); bp = h2@wb^T + fc1_b -> eb = exp(2bp)
    gemm_kernel<<<dim3(16,2,2), 256, 0, stream>>>(h2, 256,
        fc1_w, fc1_w + 256, 512,
        nullptr, nullptr, fc1_b, nullptr,
        ea, eb, 100, 100, 1, 0);
    pair_kernel<<<dim3(4,4,16), 256, 0, stream>>>(ea, eb, fc2_w, fc2_b, (float*)d_out);
}

// Round 7
// 396.643 us; speedup vs baseline: 1.3004x; 1.0016x over previous
//
#include <hip/hip_runtime.h>

typedef float v2f __attribute__((ext_vector_type(2)));

__device__ __forceinline__ float frcp(float x){ return __builtin_amdgcn_rcpf(x); }
__device__ __forceinline__ float fexp2(float x){ return __builtin_amdgcn_exp2f(x); }
// sigmoid(x) = 1/(1+e^-x);  tanh(x) = 1 - 2/(e^{2x}+1)
__device__ __forceinline__ float sigf(float x){ return frcp(1.f + fexp2(-1.4426950408889634f*x)); }
__device__ __forceinline__ float tanh_(float x){ return 1.f - 2.f*frcp(1.f + fexp2(2.8853900817779268f*x)); }

// ---------------- embedding gather + concat -> x[b*128+t][128] fp32 ----------------
__global__ __launch_bounds__(256) void embed_kernel(
    const int* __restrict__ widx, const int* __restrict__ pidx,
    const float* __restrict__ wemb, const float* __restrict__ temb,
    float* __restrict__ x)
{
    int gid = blockIdx.x*256 + threadIdx.x;   // 262144 total
    int bt = gid >> 7, c = gid & 127;
    float v;
    if (c < 100) v = wemb[(size_t)widx[bt]*100 + c];
    else         v = temb[(size_t)pidx[bt]*28 + (c-100)];
    x[gid] = v;
}

// ---------------- generic C[m][n] = sum_k A[m][k]*B[n][k] (+biases) (opt exp(2x)) --------
// M fixed 2048 (grid.x=16, BM=128). grid.z selects B/bias/C set. BN=64, BK=16.
// permflag: output column p holds gate-row gr(p) = (p&3)*128 + (p>>2) (for LSTM layout).
// As columns swizzled g(m)=m+4*(m>>5): the unswizzled read As[kk][tm*8] put 16 b128 chunks
// on 4 bank-quads (4-way conflict); g() spreads them 2-way (free on CDNA4).
__global__ __launch_bounds__(256) void gemm_kernel(
    const float* __restrict__ A, int K,
    const float* __restrict__ B0, const float* __restrict__ B1, int ldb,
    const float* __restrict__ bias0a, const float* __restrict__ bias0b,
    const float* __restrict__ bias1a, const float* __restrict__ bias1b,
    float* __restrict__ C0, float* __restrict__ C1, int ldc, int N,
    int expflag, int permflag)
{
    __shared__ float As[16][140];   // [k][g(m)], g(m)=m+4*(m>>5), max 139
    __shared__ float Bs[16][68];    // [k][n]
    const int z = blockIdx.z;
    const float* B  = z ? B1 : B0;
    const float* ba = z ? bias1a : bias0a;
    const float* bb = z ? bias1b : bias0b;
    float* C = z ? C1 : C0;
    const int m0 = blockIdx.x * 128;
    const int n0 = blockIdx.y * 64;
    const int tx = threadIdx.x;
    const int tm = tx & 15, tn = tx >> 4;       // 8x4 micro-tile
    const int arow = tx >> 1, akq = (tx & 1) * 8;
    const int brow = tx >> 2, bkq = (tx & 3) * 4;
    const int g_arow = arow + 4*(arow >> 5);
    const int rbase = tm*8 + 4*(tm >> 2);       // = g(tm*8)
    float acc[8][4];
    #pragma unroll
    for (int r=0;r<8;++r){
        #pragma unroll
        for (int c=0;c<4;++c) acc[r][c]=0.f; }
    const int bn = n0 + brow;
    const int brow_src = permflag ? ((bn & 3)*128 + (bn >> 2)) : bn;
    for (int k0 = 0; k0 < K; k0 += 16) {
        const float* ap = A + (size_t)(m0+arow)*K + k0 + akq;
        float4 a0 = *(const float4*)ap;
        float4 a1 = *(const float4*)(ap+4);
        float4 bv = make_float4(0.f,0.f,0.f,0.f);
        if (bn < N) {
            const float* bp = B + (size_t)brow_src*ldb + k0 + bkq;
            bv = *(const float4*)bp;
        }
        __syncthreads();
        As[akq+0][g_arow]=a0.x; As[akq+1][g_arow]=a0.y; As[akq+2][g_arow]=a0.z; As[akq+3][g_arow]=a0.w;
        As[akq+4][g_arow]=a1.x; As[akq+5][g_arow]=a1.y; As[akq+6][g_arow]=a1.z; As[akq+7][g_arow]=a1.w;
        Bs[bkq+0][brow]=bv.x; Bs[bkq+1][brow]=bv.y; Bs[bkq+2][brow]=bv.z; Bs[bkq+3][brow]=bv.w;
        __syncthreads();
        #pragma unroll
        for (int kk = 0; kk < 16; ++kk) {
            float4 av0 = *(const float4*)&As[kk][rbase];
            float4 av1 = *(const float4*)&As[kk][rbase+4];
            float4 bvv = *(const float4*)&Bs[kk][tn*4];
            float a[8] = {av0.x,av0.y,av0.z,av0.w,av1.x,av1.y,av1.z,av1.w};
            float b[4] = {bvv.x,bvv.y,bvv.z,bvv.w};
            #pragma unroll
            for (int r=0;r<8;++r){
                #pragma unroll
                for (int c=0;c<4;++c)
                    acc[r][c] = fmaf(a[r], b[c], acc[r][c]);
            }
        }
    }
    float bias[4];
    #pragma unroll
    for (int c=0;c<4;++c) {
        int n = n0 + tn*4 + c;
        int nsrc = permflag ? ((n & 3)*128 + (n >> 2)) : n;
        float v = 0.f;
        if (n < N) {
            if (ba) v += ba[nsrc];
            if (bb) v += bb[nsrc];
        }
        bias[c] = v;
    }
    #pragma unroll
    for (int r=0;r<8;++r) {
        int m = m0 + tm*8 + r;
        float v[4];
        #pragma unroll
        for (int c=0;c<4;++c) {
            float t = acc[r][c] + bias[c];
            if (expflag) t = fexp2(fminf(fmaxf(t,-40.f),40.f)*2.8853900817779268f); // e^{2t}
            v[c] = t;
        }
        int n = n0 + tn*4;
        if (n + 3 < N) {
            float4 st; st.x=v[0]; st.y=v[1]; st.z=v[2]; st.w=v[3];
            *(float4*)&C[(size_t)m*ldc + n] = st;
        } else {
            #pragma unroll
            for (int c=0;c<4;++c) if (n+c < N) C[(size_t)m*ldc + n + c] = v[c];
        }
    }
}

// ---------------- LSTM: one block per (b, dir) -------------------------------------------
// Thread t: half = t&1 (k-range [64*half,64*half+64)), p = t>>1, gate = p&3, rp = p>>2.
// Thread covers TWO gate-rows (gate*128 + 2rp, +1) over its k-half; row pair packed as
// float2 -> v_pk_fma_f32. w = 64 x float2 = 128 VGPRs, PINNED via in-loop empty asm
// ("+v"): makes w loop-carried so the allocator cannot re-sink the (invariant) weight
// loads into the loop -- rounds 2-6 all showed it doing exactly that (VGPR_Count 84-120).
// h_lds layout k + 4*(k>>6): upper k-half at +68 floats, so the wave's two broadcast
// addresses hit disjoint bank quads (round 6: 2.1M conflict-cycles from offsets 0/256).
// Combine: k-halves via shfl_xor(1) (DPP); gates via 4 shfls in 8-lane group; 1 barrier/step.
__global__ __launch_bounds__(512, 2)
void lstm_kernel(
    const float* __restrict__ xp,      // [dir][2048][512] permuted cols (col 4r+g <- gate row g*128+r)
    const float* __restrict__ whh_f, const float* __restrict__ whh_b,
    float* __restrict__ hcat)          // [16][128][256]
{
    const int b = blockIdx.x & 15;
    const int dir = blockIdx.x >> 4;
    const int t = threadIdx.x;
    const int half = t & 1;
    const int p = t >> 1;
    const int gate = p & 3, rp = p >> 2;      // rows r0=2rp, r1=2rp+1
    const int lane = t & 63, gbase = lane & ~7;
    const float* whh = dir ? whh_b : whh_f;
    // activation constants: sig(x)=1/(1+2^(-x*log2e)); tanh(x)=1-2/(1+2^(2x*log2e))
    const float kexp = (gate == 2) ? 2.8853900817779268f : -1.4426950408889634f;
    const float mA   = (gate == 2) ? -2.f : 1.f;
    const float mB   = (gate == 2) ?  1.f : 0.f;

    // load w: rows gr0=gate*128+2rp and gr0+1, k in [64*half, 64*half+64), packed (row0,row1)
    v2f w[64];
    {
        const float* wr = whh + (size_t)(gate*128 + 2*rp)*128 + 64*half;
        #pragma unroll
        for (int j = 0; j < 64; j += 4) {
            float4 a = *(const float4*)(wr + j);
            float4 bq = *(const float4*)(wr + 128 + j);
            w[j+0] = (v2f){a.x, bq.x};
            w[j+1] = (v2f){a.y, bq.y};
            w[j+2] = (v2f){a.z, bq.z};
            w[j+3] = (v2f){a.w, bq.w};
        }
    }

    __shared__ float h_lds[2][136];            // index k + 4*(k>>6)
    float c = 0.f;
    if (t < 128) h_lds[0][t + 4*(t >> 6)] = 0.f;
    __syncthreads();
    const float* xpd = xp + (size_t)dir*(2048*512) + (size_t)b*(128*512);
    // this thread's own row and xp column (permuted layout: col = 4*row + gate)
    const int myrow = 2*rp + half;
    const int mycol = 4*myrow + gate;
    const int mystore = myrow + 4*(myrow >> 6);
    float xpv = xpd[(dir ? 127 : 0)*512 + mycol];
    const int koff = 68*half;                  // 64*half + 4*half (swizzled base)
    for (int s = 0; s < 128; ++s) {
        // pin w: loop-carried redefinition, forces register residency across the backedge
        #pragma unroll
        for (int j = 0; j < 64; ++j) asm volatile("" : "+v"(w[j]));
        const int ts = dir ? (127 - s) : s;
        // branchless prefetch of next step's xp (clamped; last-iter load is harmless)
        const int tsn = dir ? (126 - s < 0 ? 0 : 126 - s) : (s + 1 > 127 ? 127 : s + 1);
        float xnext = xpd[tsn*512 + mycol];
        const float* hb = &h_lds[s & 1][koff];
        v2f da = (v2f){0.f,0.f}, db = (v2f){0.f,0.f};
        #pragma unroll
        for (int j = 0; j < 64; j += 4) {
            float4 h4 = *(const float4*)&hb[j];     // 2-addr broadcast, disjoint bank quads
            da += w[j+0] * (v2f){h4.x, h4.x};
            db += w[j+1] * (v2f){h4.y, h4.y};
            da += w[j+2] * (v2f){h4.z, h4.z};
            db += w[j+3] * (v2f){h4.w, h4.w};
        }
        v2f d = da + db;                            // (row0 partial, row1 partial) over k-half
        float d0 = d.x + __shfl_xor(d.x, 1, 64);    // full dots (both halves have them)
        float d1 = d.y + __shfl_xor(d.y, 1, 64);
        float dot = xpv + (half ? d1 : d0);
        float act = fmaf(mA, frcp(1.f + fexp2(kexp*dot)), mB);
        // gate combine: row (2rp+half)'s gate g sits at lane gbase + 2g + half
        float i_ = __shfl(act, gbase + 0 + half, 64);
        float f_ = __shfl(act, gbase + 2 + half, 64);
        float g_ = __shfl(act, gbase + 4 + half, 64);
        float o_ = __shfl(act, gbase + 6 + half, 64);
        c = f_*c + i_*g_;                           // redundant across the 4 gate-lanes of this row
        float h = o_ * tanh_(c);
        if ((lane & 7) < 2) {                        // lane gbase+0 -> row 2rp, gbase+1 -> row 2rp+1
            h_lds[(s & 1) ^ 1][mystore] = h;
            hcat[((size_t)b*128 + ts)*256 + dir*128 + myrow] = h;
        }
        xpv = xnext;
        __syncthreads();
    }
}

// ------------- pairwise scorer: out[(i*128+j)*16+b] = S + sum_k w2_k / (ea_ik*eb_jk + 1) ----
// w2[k] = -2*fc2_w[k], S = sum(fc2_w)+fc2_b computed in-block (prep fused).
__global__ __launch_bounds__(256) void pair_kernel(
    const float* __restrict__ ea, const float* __restrict__ eb,
    const float* __restrict__ fc2w, const float* __restrict__ fc2b,
    float* __restrict__ out)
{
    __shared__ float eas[32][100];
    __shared__ float ebs[32][100];
    __shared__ float w2s[100];
    __shared__ float red[128];
    const int it = blockIdx.x * 32, jt = blockIdx.y * 32, b = blockIdx.z;
    const int tx = threadIdx.x;
    const float* eab = ea + (size_t)b*12800;
    const float* ebb = eb + (size_t)b*12800;
    for (int idx = tx; idx < 3200; idx += 256) {
        int r = idx / 100;
        int cc = idx - r*100;
        eas[r][cc] = eab[(it + r)*100 + cc];
        ebs[r][cc] = ebb[(jt + r)*100 + cc];
    }
    if (tx < 128) {
        float wv = (tx < 100) ? fc2w[tx] : 0.f;
        if (tx < 100) w2s[tx] = -2.f*wv;
        red[tx] = wv;
    }
    __syncthreads();
    for (int s2 = 64; s2 > 0; s2 >>= 1) {
        if (tx < s2) red[tx] += red[tx+s2];
        __syncthreads();
    }
    const float S = red[0] + fc2b[0];
    const int jp = tx & 15, ip = tx >> 4;
    const int i0 = ip*2, j0 = jp*2;
    float acc00=S, acc01=S, acc10=S, acc11=S;
    #pragma unroll
    for (int k = 0; k < 100; k += 4) {
        float4 A0 = *(const float4*)&eas[i0][k];
        float4 A1 = *(const float4*)&eas[i0+1][k];
        float4 B0 = *(const float4*)&ebs[j0][k];
        float4 B1 = *(const float4*)&ebs[j0+1][k];
        float4 W  = *(const float4*)&w2s[k];
        acc00 = fmaf(W.x, frcp(fmaf(A0.x,B0.x,1.f)), acc00);
        acc01 = fmaf(W.x, frcp(fmaf(A0.x,B1.x,1.f)), acc01);
        acc10 = fmaf(W.x, frcp(fmaf(A1.x,B0.x,1.f)), acc10);
        acc11 = fmaf(W.x, frcp(fmaf(A1.x,B1.x,1.f)), acc11);
        acc00 = fmaf(W.y, frcp(fmaf(A0.y,B0.y,1.f)), acc00);
        acc01 = fmaf(W.y, frcp(fmaf(A0.y,B1.y,1.f)), acc01);
        acc10 = fmaf(W.y, frcp(fmaf(A1.y,B0.y,1.f)), acc10);
        acc11 = fmaf(W.y, frcp(fmaf(A1.y,B1.y,1.f)), acc11);
        acc00 = fmaf(W.z, frcp(fmaf(A0.z,B0.z,1.f)), acc00);
        acc01 = fmaf(W.z, frcp(fmaf(A0.z,B1.z,1.f)), acc01);
        acc10 = fmaf(W.z, frcp(fmaf(A1.z,B0.z,1.f)), acc10);
        acc11 = fmaf(W.z, frcp(fmaf(A1.z,B1.z,1.f)), acc11);
        acc00 = fmaf(W.w, frcp(fmaf(A0.w,B0.w,1.f)), acc00);
        acc01 = fmaf(W.w, frcp(fmaf(A0.w,B1.w,1.f)), acc01);
        acc10 = fmaf(W.w, frcp(fmaf(A1.w,B0.w,1.f)), acc10);
        acc11 = fmaf(W.w, frcp(fmaf(A1.w,B1.w,1.f)), acc11);
    }
    const int gi0 = it + i0, gj0 = jt + j0;
    out[((size_t)(gi0  )*128 + gj0  )*16 + b] = acc00;
    out[((size_t)(gi0  )*128 + gj0+1)*16 + b] = acc01;
    out[((size_t)(gi0+1)*128 + gj0  )*16 + b] = acc10;
    out[((size_t)(gi0+1)*128 + gj0+1)*16 + b] = acc11;
}

extern "C" void kernel_launch(void* const* d_in, const int* in_sizes, int n_in,
                              void* d_out, int out_size, void* d_ws, size_t ws_size,
                              hipStream_t stream)
{
    (void)in_sizes; (void)n_in; (void)out_size; (void)ws_size;
    const int*   widx = (const int*)d_in[0];
    const int*   pidx = (const int*)d_in[1];
    const float* wemb = (const float*)d_in[4];
    const float* temb = (const float*)d_in[5];
    const float* w_ih_l0f = (const float*)d_in[6];
    const float* w_hh_l0f = (const float*)d_in[7];
    const float* b_ih_l0f = (const float*)d_in[8];
    const float* b_hh_l0f = (const float*)d_in[9];
    const float* w_ih_l0b = (const float*)d_in[10];
    const float* w_hh_l0b = (const float*)d_in[11];
    const float* b_ih_l0b = (const float*)d_in[12];
    const float* b_hh_l0b = (const float*)d_in[13];
    const float* w_ih_l1f = (const float*)d_in[14];
    const float* w_hh_l1f = (const float*)d_in[15];
    const float* b_ih_l1f = (const float*)d_in[16];
    const float* b_hh_l1f = (const float*)d_in[17];
    const float* w_ih_l1b = (const float*)d_in[18];
    const float* w_hh_l1b = (const float*)d_in[19];
    const float* b_ih_l1b = (const float*)d_in[20];
    const float* b_hh_l1b = (const float*)d_in[21];
    const float* fc1_w = (const float*)d_in[22];
    const float* fc1_b = (const float*)d_in[23];
    const float* fc2_w = (const float*)d_in[24];
    const float* fc2_b = (const float*)d_in[25];

    float* ws  = (float*)d_ws;
    float* x   = ws;                  // 262144
    float* xp0 = x + 262144;          // 2 * 1048576
    float* h1  = xp0 + 2097152;       // 524288
    float* xp1 = h1 + 524288;         // 2 * 1048576
    float* h2  = xp1 + 2097152;       // 524288
    float* ea  = h2 + 524288;         // 204800
    float* eb  = ea + 204800;         // 204800
    // total ~5.92M floats = 23.7 MB

    embed_kernel<<<1024, 256, 0, stream>>>(widx, pidx, wemb, temb, x);
    // layer 0 input projections (both dirs in grid.z), gate-permuted columns
    gemm_kernel<<<dim3(16,8,2), 256, 0, stream>>>(x, 128,
        w_ih_l0f, w_ih_l0b, 128,
        b_ih_l0f, b_hh_l0f, b_ih_l0b, b_hh_l0b,
        xp0, xp0 + 1048576, 512, 512, 0, 1);
    lstm_kernel<<<32, 512, 0, stream>>>(xp0, w_hh_l0f, w_hh_l0b, h1);
    // layer 1 input projections, gate-permuted columns
    gemm_kernel<<<dim3(16,8,2), 256, 0, stream>>>(h1, 256,
        w_ih_l1f, w_ih_l1b, 256,
        b_ih_l1f, b_hh_l1f, b_ih_l1b, b_hh_l1b,
        xp1, xp1 + 1048576, 512, 512, 0, 1);
    lstm_kernel<<<32, 512, 0, stream>>>(xp1, w_hh_l1f, w_hh_l1b, h2);
    // fc1: a = h2@wa^T -> ea = exp(2a); bp = h2@wb^T + fc1_b -> eb = exp(2bp)
    gemm_kernel<<<dim3(16,2,2), 256, 0, stream>>>(h2, 256,
        fc1_w, fc1_w + 256, 512,
        nullptr, nullptr, fc1_b, nullptr,
        ea, eb, 100, 100, 1, 0);
    pair_kernel<<<dim3(4,4,16), 256, 0, stream>>>(ea, eb, fc2_w, fc2_b, (float*)d_out);
}

// Round 8
// 392.865 us; speedup vs baseline: 1.3129x; 1.0096x over previous
//
#include <hip/hip_runtime.h>

typedef float v2f __attribute__((ext_vector_type(2)));

__device__ __forceinline__ float frcp(float x){ return __builtin_amdgcn_rcpf(x); }
__device__ __forceinline__ float fexp2(float x){ return __builtin_amdgcn_exp2f(x); }
// sigmoid(x) = 1/(1+e^-x);  tanh(x) = 1 - 2/(e^{2x}+1)
__device__ __forceinline__ float sigf(float x){ return frcp(1.f + fexp2(-1.4426950408889634f*x)); }
__device__ __forceinline__ float tanh_(float x){ return 1.f - 2.f*frcp(1.f + fexp2(2.8853900817779268f*x)); }

// ---------------- embedding gather + concat -> x[b*128+t][128] fp32 ----------------
__global__ __launch_bounds__(256) void embed_kernel(
    const int* __restrict__ widx, const int* __restrict__ pidx,
    const float* __restrict__ wemb, const float* __restrict__ temb,
    float* __restrict__ x)
{
    int gid = blockIdx.x*256 + threadIdx.x;   // 262144 total
    int bt = gid >> 7, c = gid & 127;
    float v;
    if (c < 100) v = wemb[(size_t)widx[bt]*100 + c];
    else         v = temb[(size_t)pidx[bt]*28 + (c-100)];
    x[gid] = v;
}

// ---------------- generic C[m][n] = sum_k A[m][k]*B[n][k] (+biases) (opt exp(2x)) --------
// M fixed 2048 (grid.x=16, BM=128). grid.z selects B/bias/C set. BN=64, BK=16.
// permflag: output column p holds gate-row gr(p) = (p&3)*128 + (p>>2) (for LSTM layout).
// As columns swizzled g(m)=m+4*(m>>5) (round 7: 4-way -> 2-way bank spread).
__global__ __launch_bounds__(256) void gemm_kernel(
    const float* __restrict__ A, int K,
    const float* __restrict__ B0, const float* __restrict__ B1, int ldb,
    const float* __restrict__ bias0a, const float* __restrict__ bias0b,
    const float* __restrict__ bias1a, const float* __restrict__ bias1b,
    float* __restrict__ C0, float* __restrict__ C1, int ldc, int N,
    int expflag, int permflag)
{
    __shared__ float As[16][140];   // [k][g(m)], g(m)=m+4*(m>>5), max 139
    __shared__ float Bs[16][68];    // [k][n]
    const int z = blockIdx.z;
    const float* B  = z ? B1 : B0;
    const float* ba = z ? bias1a : bias0a;
    const float* bb = z ? bias1b : bias0b;
    float* C = z ? C1 : C0;
    const int m0 = blockIdx.x * 128;
    const int n0 = blockIdx.y * 64;
    const int tx = threadIdx.x;
    const int tm = tx & 15, tn = tx >> 4;       // 8x4 micro-tile
    const int arow = tx >> 1, akq = (tx & 1) * 8;
    const int brow = tx >> 2, bkq = (tx & 3) * 4;
    const int g_arow = arow + 4*(arow >> 5);
    const int rbase = tm*8 + 4*(tm >> 2);       // = g(tm*8)
    float acc[8][4];
    #pragma unroll
    for (int r=0;r<8;++r){
        #pragma unroll
        for (int c=0;c<4;++c) acc[r][c]=0.f; }
    const int bn = n0 + brow;
    const int brow_src = permflag ? ((bn & 3)*128 + (bn >> 2)) : bn;
    for (int k0 = 0; k0 < K; k0 += 16) {
        const float* ap = A + (size_t)(m0+arow)*K + k0 + akq;
        float4 a0 = *(const float4*)ap;
        float4 a1 = *(const float4*)(ap+4);
        float4 bv = make_float4(0.f,0.f,0.f,0.f);
        if (bn < N) {
            const float* bp = B + (size_t)brow_src*ldb + k0 + bkq;
            bv = *(const float4*)bp;
        }
        __syncthreads();
        As[akq+0][g_arow]=a0.x; As[akq+1][g_arow]=a0.y; As[akq+2][g_arow]=a0.z; As[akq+3][g_arow]=a0.w;
        As[akq+4][g_arow]=a1.x; As[akq+5][g_arow]=a1.y; As[akq+6][g_arow]=a1.z; As[akq+7][g_arow]=a1.w;
        Bs[bkq+0][brow]=bv.x; Bs[bkq+1][brow]=bv.y; Bs[bkq+2][brow]=bv.z; Bs[bkq+3][brow]=bv.w;
        __syncthreads();
        #pragma unroll
        for (int kk = 0; kk < 16; ++kk) {
            float4 av0 = *(const float4*)&As[kk][rbase];
            float4 av1 = *(const float4*)&As[kk][rbase+4];
            float4 bvv = *(const float4*)&Bs[kk][tn*4];
            float a[8] = {av0.x,av0.y,av0.z,av0.w,av1.x,av1.y,av1.z,av1.w};
            float b[4] = {bvv.x,bvv.y,bvv.z,bvv.w};
            #pragma unroll
            for (int r=0;r<8;++r){
                #pragma unroll
                for (int c=0;c<4;++c)
                    acc[r][c] = fmaf(a[r], b[c], acc[r][c]);
            }
        }
    }
    float bias[4];
    #pragma unroll
    for (int c=0;c<4;++c) {
        int n = n0 + tn*4 + c;
        int nsrc = permflag ? ((n & 3)*128 + (n >> 2)) : n;
        float v = 0.f;
        if (n < N) {
            if (ba) v += ba[nsrc];
            if (bb) v += bb[nsrc];
        }
        bias[c] = v;
    }
    #pragma unroll
    for (int r=0;r<8;++r) {
        int m = m0 + tm*8 + r;
        float v[4];
        #pragma unroll
        for (int c=0;c<4;++c) {
            float t = acc[r][c] + bias[c];
            if (expflag) t = fexp2(fminf(fmaxf(t,-40.f),40.f)*2.8853900817779268f); // e^{2t}
            v[c] = t;
        }
        int n = n0 + tn*4;
        if (n + 3 < N) {
            float4 st; st.x=v[0]; st.y=v[1]; st.z=v[2]; st.w=v[3];
            *(float4*)&C[(size_t)m*ldc + n] = st;
        } else {
            #pragma unroll
            for (int c=0;c<4;++c) if (n+c < N) C[(size_t)m*ldc + n + c] = v[c];
        }
    }
}

// ---------------- LSTM: one block per (b, dir), quarter-k thread map ----------------------
// Thread t: q = t&3 (k in [32q,32q+32)), gc = (t>>2)&3 (gate CODE: 0=i,1=gcell,2=f,3=o),
// rp = t>>4 (rows 4rp..4rp+3). Thread holds 4 weight rows x 32 k as 2 x v2f[32] (128 VGPRs).
// RESIDENCY FIX (rounds 2-7 war): whh/hcat are NOT __restrict -> the in-loop hcat store
// may-alias the weight loads -> rematerializing/sinking the loads into the loop is ILLEGAL.
// The compiler must keep w live (pressure ~170 < 256 budget from launch_bounds(512,2)).
// Per step: 8 ds_read_b128 (quarter-k, half of round 7); k-combine = shfl_xor 1,2 (quad DPP,
// VALU pipe); gate-combine = 2 ds_swizzle (xor4: i<->gcell,f<->o; xor8: i<->f,gcell<->o).
// Routing (verified lane algebra): o1=xor4(act); v1 = gc<2 ? act*o1 (=P) : sigma_f
// (f: own act, o: o1); o2=xor8(v1); then c' = A*c+B with A = {o2,o2,act,o1}[gc] (all =sigma_f),
// B = {v1,v1,o2,o2}[gc] (all =P). h = sigma_o*tanh(c') valid on gc 2,3; gc==2 lanes write.
// h_lds index f(k)=k+4*(k>>5): quarters land on distinct bank quads (conflict-free b128).
__global__ __launch_bounds__(512, 2)
void lstm_kernel(
    const float* __restrict__ xp,      // [dir][2048][512] permuted cols (col 4r+gp, gp=pytorch gate)
    const float* whh_f, const float* whh_b,   // no __restrict (aliasing pin, see above)
    float* hcat)                              // [16][128][256], no __restrict
{
    const int b = blockIdx.x & 15;
    const int dir = blockIdx.x >> 4;
    const int t = threadIdx.x;
    const int q  = t & 3;
    const int gc = (t >> 2) & 3;
    const int rp = t >> 4;
    const float* whh = dir ? whh_b : whh_f;
    // gate code -> pytorch gate block (i,f,g,o order in weights): 0->i(0),1->gcell(2),2->f(1),3->o(3)
    const int G = (gc == 0) ? 0 : (gc == 1) ? 2 : (gc == 2) ? 1 : 3;
    // activation constants: sigmoid for i,f,o; tanh form for gcell
    const float kexp = (gc == 1) ? 2.8853900817779268f : -1.4426950408889634f;
    const float mA   = (gc == 1) ? -2.f : 1.f;
    const float mB   = (gc == 1) ?  1.f : 0.f;

    // load w: pytorch rows G*128 + 4rp + {0,1,2,3}, k in [32q, 32q+32)
    v2f wA[32], wB[32];   // wA=(row0,row1), wB=(row2,row3)
    {
        const float* wr = whh + (size_t)(G*128 + 4*rp)*128 + 32*q;
        #pragma unroll
        for (int j = 0; j < 32; j += 4) {
            float4 r0 = *(const float4*)(wr + j);
            float4 r1 = *(const float4*)(wr + 128 + j);
            float4 r2 = *(const float4*)(wr + 256 + j);
            float4 r3 = *(const float4*)(wr + 384 + j);
            wA[j+0] = (v2f){r0.x, r1.x}; wB[j+0] = (v2f){r2.x, r3.x};
            wA[j+1] = (v2f){r0.y, r1.y}; wB[j+1] = (v2f){r2.y, r3.y};
            wA[j+2] = (v2f){r0.z, r1.z}; wB[j+2] = (v2f){r2.z, r3.z};
            wA[j+3] = (v2f){r0.w, r1.w}; wB[j+3] = (v2f){r2.w, r3.w};
        }
    }

    __shared__ float h_lds[2][140];            // index f(k) = k + 4*(k>>5)
    float c = 0.f;
    if (t < 128) h_lds[0][t + 4*(t >> 5)] = 0.f;
    __syncthreads();

    const float* xpd = xp + (size_t)dir*(2048*512) + (size_t)b*(128*512);
    const int myrow = 4*rp + q;                // row this lane owns post-combine
    const int mycol = 4*myrow + G;             // xp permuted column
    const int mystore = myrow + 4*(myrow >> 5);
    float xpv = xpd[(dir ? 127 : 0)*512 + mycol];

    for (int s = 0; s < 128; ++s) {
        const int ts = dir ? (127 - s) : s;
        const int tsn = dir ? (126 - s < 0 ? 0 : 126 - s) : (s + 1 > 127 ? 127 : s + 1);
        float xnext = xpd[tsn*512 + mycol];    // prefetch (xp is restrict -> hoistable)
        const float* hb = &h_lds[s & 1][36*q]; // = f(32q), quarters on distinct bank quads
        v2f aA = (v2f){0.f,0.f}, aB = (v2f){0.f,0.f};
        #pragma unroll
        for (int j = 0; j < 32; j += 4) {
            float4 h4 = *(const float4*)&hb[j];
            aA += wA[j+0] * (v2f){h4.x, h4.x};  aB += wB[j+0] * (v2f){h4.x, h4.x};
            aA += wA[j+1] * (v2f){h4.y, h4.y};  aB += wB[j+1] * (v2f){h4.y, h4.y};
            aA += wA[j+2] * (v2f){h4.z, h4.z};  aB += wB[j+2] * (v2f){h4.z, h4.z};
            aA += wA[j+3] * (v2f){h4.w, h4.w};  aB += wB[j+3] * (v2f){h4.w, h4.w};
        }
        // k-combine over q bits (lane xor 1,2 -> quad_perm DPP)
        float a0 = aA.x, a1 = aA.y, a2 = aB.x, a3 = aB.y;
        a0 += __shfl_xor(a0, 1, 64); a1 += __shfl_xor(a1, 1, 64);
        a2 += __shfl_xor(a2, 1, 64); a3 += __shfl_xor(a3, 1, 64);
        a0 += __shfl_xor(a0, 2, 64); a1 += __shfl_xor(a1, 2, 64);
        a2 += __shfl_xor(a2, 2, 64); a3 += __shfl_xor(a3, 2, 64);
        // lane keeps row 4rp+q
        float dsel = (q & 2) ? ((q & 1) ? a3 : a2) : ((q & 1) ? a1 : a0);
        float dot = xpv + dsel;
        float act = fmaf(mA, frcp(1.f + fexp2(kexp*dot)), mB);
        // gate combine (see header comment)
        float o1 = __uint_as_float(__builtin_amdgcn_ds_swizzle(__float_as_uint(act), 0x101F)); // xor4
        float v1 = (gc < 2) ? act * o1 : ((gc == 2) ? act : o1);
        float o2 = __uint_as_float(__builtin_amdgcn_ds_swizzle(__float_as_uint(v1), 0x201F));  // xor8
        float Af = (gc < 2) ? o2 : ((gc == 2) ? act : o1);   // sigma_f on every lane
        float Bf = (gc < 2) ? v1 : o2;                       // P on every lane
        c = fmaf(Af, c, Bf);
        float th = tanh_(c);
        float sigo = (gc == 2) ? o1 : act;                   // valid on gc 2,3
        float h = sigo * th;
        if (gc == 2) {
            h_lds[(s & 1) ^ 1][mystore] = h;
            hcat[((size_t)b*128 + ts)*256 + dir*128 + myrow] = h;
        }
        xpv = xnext;
        __syncthreads();
    }
}

// ------------- pairwise scorer: out[(i*128+j)*16+b] = S + sum_k w2_k / (ea_ik*eb_jk + 1) ----
// w2[k] = -2*fc2_w[k], S = sum(fc2_w)+fc2_b computed in-block (prep fused).
__global__ __launch_bounds__(256) void pair_kernel(
    const float* __restrict__ ea, const float* __restrict__ eb,
    const float* __restrict__ fc2w, const float* __restrict__ fc2b,
    float* __restrict__ out)
{
    __shared__ float eas[32][100];
    __shared__ float ebs[32][100];
    __shared__ float w2s[100];
    __shared__ float red[128];
    const int it = blockIdx.x * 32, jt = blockIdx.y * 32, b = blockIdx.z;
    const int tx = threadIdx.x;
    const float* eab = ea + (size_t)b*12800;
    const float* ebb = eb + (size_t)b*12800;
    for (int idx = tx; idx < 3200; idx += 256) {
        int r = idx / 100;
        int cc = idx - r*100;
        eas[r][cc] = eab[(it + r)*100 + cc];
        ebs[r][cc] = ebb[(jt + r)*100 + cc];
    }
    if (tx < 128) {
        float wv = (tx < 100) ? fc2w[tx] : 0.f;
        if (tx < 100) w2s[tx] = -2.f*wv;
        red[tx] = wv;
    }
    __syncthreads();
    for (int s2 = 64; s2 > 0; s2 >>= 1) {
        if (tx < s2) red[tx] += red[tx+s2];
        __syncthreads();
    }
    const float S = red[0] + fc2b[0];
    const int jp = tx & 15, ip = tx >> 4;
    const int i0 = ip*2, j0 = jp*2;
    float acc00=S, acc01=S, acc10=S, acc11=S;
    #pragma unroll
    for (int k = 0; k < 100; k += 4) {
        float4 A0 = *(const float4*)&eas[i0][k];
        float4 A1 = *(const float4*)&eas[i0+1][k];
        float4 B0 = *(const float4*)&ebs[j0][k];
        float4 B1 = *(const float4*)&ebs[j0+1][k];
        float4 W  = *(const float4*)&w2s[k];
        acc00 = fmaf(W.x, frcp(fmaf(A0.x,B0.x,1.f)), acc00);
        acc01 = fmaf(W.x, frcp(fmaf(A0.x,B1.x,1.f)), acc01);
        acc10 = fmaf(W.x, frcp(fmaf(A1.x,B0.x,1.f)), acc10);
        acc11 = fmaf(W.x, frcp(fmaf(A1.x,B1.x,1.f)), acc11);
        acc00 = fmaf(W.y, frcp(fmaf(A0.y,B0.y,1.f)), acc00);
        acc01 = fmaf(W.y, frcp(fmaf(A0.y,B1.y,1.f)), acc01);
        acc10 = fmaf(W.y, frcp(fmaf(A1.y,B0.y,1.f)), acc10);
        acc11 = fmaf(W.y, frcp(fmaf(A1.y,B1.y,1.f)), acc11);
        acc00 = fmaf(W.z, frcp(fmaf(A0.z,B0.z,1.f)), acc00);
        acc01 = fmaf(W.z, frcp(fmaf(A0.z,B1.z,1.f)), acc01);
        acc10 = fmaf(W.z, frcp(fmaf(A1.z,B0.z,1.f)), acc10);
        acc11 = fmaf(W.z, frcp(fmaf(A1.z,B1.z,1.f)), acc11);
        acc00 = fmaf(W.w, frcp(fmaf(A0.w,B0.w,1.f)), acc00);
        acc01 = fmaf(W.w, frcp(fmaf(A0.w,B1.w,1.f)), acc01);
        acc10 = fmaf(W.w, frcp(fmaf(A1.w,B0.w,1.f)), acc10);
        acc11 = fmaf(W.w, frcp(fmaf(A1.w,B1.w,1.f)), acc11);
    }
    const int gi0 = it + i0, gj0 = jt + j0;
    out[((size_t)(gi0  )*128 + gj0  )*16 + b] = acc00;
    out[((size_t)(gi0  )*128 + gj0+1)*16 + b] = acc01;
    out[((size_t)(gi0+1)*128 + gj0  )*16 + b] = acc10;
    out[((size_t)(gi0+1)*128 + gj0+1)*16 + b] = acc11;
}

extern "C" void kernel_launch(void* const* d_in, const int* in_sizes, int n_in,
                              void* d_out, int out_size, void* d_ws, size_t ws_size,
                              hipStream_t stream)
{
    (void)in_sizes; (void)n_in; (void)out_size; (void)ws_size;
    const int*   widx = (const int*)d_in[0];
    const int*   pidx = (const int*)d_in[1];
    const float* wemb = (const float*)d_in[4];
    const float* temb = (const float*)d_in[5];
    const float* w_ih_l0f = (const float*)d_in[6];
    const float* w_hh_l0f = (const float*)d_in[7];
    const float* b_ih_l0f = (const float*)d_in[8];
    const float* b_hh_l0f = (const float*)d_in[9];
    const float* w_ih_l0b = (const float*)d_in[10];
    const float* w_hh_l0b = (const float*)d_in[11];
    const float* b_ih_l0b = (const float*)d_in[12];
    const float* b_hh_l0b = (const float*)d_in[13];
    const float* w_ih_l1f = (const float*)d_in[14];
    const float* w_hh_l1f = (const float*)d_in[15];
    const float* b_ih_l1f = (const float*)d_in[16];
    const float* b_hh_l1f = (const float*)d_in[17];
    const float* w_ih_l1b = (const float*)d_in[18];
    const float* w_hh_l1b = (const float*)d_in[19];
    const float* b_ih_l1b = (const float*)d_in[20];
    const float* b_hh_l1b = (const float*)d_in[21];
    const float* fc1_w = (const float*)d_in[22];
    const float* fc1_b = (const float*)d_in[23];
    const float* fc2_w = (const float*)d_in[24];
    const float* fc2_b = (const float*)d_in[25];

    float* ws  = (float*)d_ws;
    float* x   = ws;                  // 262144
    float* xp0 = x + 262144;          // 2 * 1048576
    float* h1  = xp0 + 2097152;       // 524288
    float* xp1 = h1 + 524288;         // 2 * 1048576
    float* h2  = xp1 + 2097152;       // 524288
    float* ea  = h2 + 524288;         // 204800
    float* eb  = ea + 204800;         // 204800
    // total ~5.92M floats = 23.7 MB

    embed_kernel<<<1024, 256, 0, stream>>>(widx, pidx, wemb, temb, x);
    // layer 0 input projections (both dirs in grid.z), gate-permuted columns
    gemm_kernel<<<dim3(16,8,2), 256, 0, stream>>>(x, 128,
        w_ih_l0f, w_ih_l0b, 128,
        b_ih_l0f, b_hh_l0f, b_ih_l0b, b_hh_l0b,
        xp0, xp0 + 1048576, 512, 512, 0, 1);
    lstm_kernel<<<32, 512, 0, stream>>>(xp0, w_hh_l0f, w_hh_l0b, h1);
    // layer 1 input projections, gate-permuted columns
    gemm_kernel<<<dim3(16,8,2), 256, 0, stream>>>(h1, 256,
        w_ih_l1f, w_ih_l1b, 256,
        b_ih_l1f, b_hh_l1f, b_ih_l1b, b_hh_l1b,
        xp1, xp1 + 1048576, 512, 512, 0, 1);
    lstm_kernel<<<32, 512, 0, stream>>>(xp1, w_hh_l1f, w_hh_l1b, h2);
    // fc1: a = h2@wa^T -> ea = exp(2a); bp = h2@wb^T + fc1_b -> eb = exp(2bp)
    gemm_kernel<<<dim3(16,2,2), 256, 0, stream>>>(h2, 256,
        fc1_w, fc1_w + 256, 512,
        nullptr, nullptr, fc1_b, nullptr,
        ea, eb, 100, 100, 1, 0);
    pair_kernel<<<dim3(4,4,16), 256, 0, stream>>>(ea, eb, fc2_w, fc2_b, (float*)d_out);
}

// Round 9
// 359.427 us; speedup vs baseline: 1.4350x; 1.0930x over previous
//
#include <hip/hip_runtime.h>

typedef float v2f __attribute__((ext_vector_type(2)));
typedef _Float16 h2 __attribute__((ext_vector_type(2)));

__device__ __forceinline__ float frcp(float x){ return __builtin_amdgcn_rcpf(x); }
__device__ __forceinline__ float fexp2(float x){ return __builtin_amdgcn_exp2f(x); }
// sigmoid(x) = 1/(1+e^-x);  tanh(x) = 1 - 2/(e^{2x}+1)
__device__ __forceinline__ float tanh_(float x){ return 1.f - 2.f*frcp(1.f + fexp2(2.8853900817779268f*x)); }

#if __has_builtin(__builtin_amdgcn_fdot2)
#define FDOT2(a,b,c) __builtin_amdgcn_fdot2((a),(b),(c),false)
#else
#define FDOT2(a,b,c) ((c) + (float)(a).x*(float)(b).x + (float)(a).y*(float)(b).y)
#endif

// ---------------- embedding gather + concat -> x[b*128+t][128] fp32 ----------------
__global__ __launch_bounds__(256) void embed_kernel(
    const int* __restrict__ widx, const int* __restrict__ pidx,
    const float* __restrict__ wemb, const float* __restrict__ temb,
    float* __restrict__ x)
{
    int gid = blockIdx.x*256 + threadIdx.x;   // 262144 total
    int bt = gid >> 7, c = gid & 127;
    float v;
    if (c < 100) v = wemb[(size_t)widx[bt]*100 + c];
    else         v = temb[(size_t)pidx[bt]*28 + (c-100)];
    x[gid] = v;
}

// ---------------- pack w_hh (both dirs) to f16 pairs in thread-native layout --------------
// wpack[dir][t][j]: t = 4r+g owns pytorch gate-row g*128+r; j-th uint = (f16 w[2j], f16 w[2j+1]).
__global__ __launch_bounds__(256) void pack_kernel(
    const float* __restrict__ whh_f, const float* __restrict__ whh_b,
    unsigned* __restrict__ wpack)
{
    int id = blockIdx.x*256 + threadIdx.x;    // 65536 total
    int d = id >> 15, t = (id >> 6) & 511, j = id & 63;
    const float* whh = d ? whh_b : whh_f;
    int r = t >> 2, g = t & 3;
    const float* src = whh + (size_t)(g*128 + r)*128 + 2*j;
    unsigned short a = __builtin_bit_cast(unsigned short, (_Float16)src[0]);
    unsigned short b = __builtin_bit_cast(unsigned short, (_Float16)src[1]);
    wpack[((size_t)d*512 + t)*64 + j] = (unsigned)a | ((unsigned)b << 16);
}

// ---------------- generic C[m][n] = sum_k A[m][k]*B[n][k] (+biases) (opt exp(2x)) --------
// M fixed 2048 (grid.x=16, BM=128). grid.z selects B/bias/C set. BN=64, BK=16.
// permflag: output column p holds gate-row gr(p) = (p&3)*128 + (p>>2) (for LSTM layout).
// As columns swizzled g(m)=m+4*(m>>5) (round 7: 4-way -> 2-way bank spread).
__global__ __launch_bounds__(256) void gemm_kernel(
    const float* __restrict__ A, int K,
    const float* __restrict__ B0, const float* __restrict__ B1, int ldb,
    const float* __restrict__ bias0a, const float* __restrict__ bias0b,
    const float* __restrict__ bias1a, const float* __restrict__ bias1b,
    float* __restrict__ C0, float* __restrict__ C1, int ldc, int N,
    int expflag, int permflag)
{
    __shared__ float As[16][140];   // [k][g(m)], g(m)=m+4*(m>>5), max 139
    __shared__ float Bs[16][68];    // [k][n]
    const int z = blockIdx.z;
    const float* B  = z ? B1 : B0;
    const float* ba = z ? bias1a : bias0a;
    const float* bb = z ? bias1b : bias0b;
    float* C = z ? C1 : C0;
    const int m0 = blockIdx.x * 128;
    const int n0 = blockIdx.y * 64;
    const int tx = threadIdx.x;
    const int tm = tx & 15, tn = tx >> 4;       // 8x4 micro-tile
    const int arow = tx >> 1, akq = (tx & 1) * 8;
    const int brow = tx >> 2, bkq = (tx & 3) * 4;
    const int g_arow = arow + 4*(arow >> 5);
    const int rbase = tm*8 + 4*(tm >> 2);       // = g(tm*8)
    float acc[8][4];
    #pragma unroll
    for (int r=0;r<8;++r){
        #pragma unroll
        for (int c=0;c<4;++c) acc[r][c]=0.f; }
    const int bn = n0 + brow;
    const int brow_src = permflag ? ((bn & 3)*128 + (bn >> 2)) : bn;
    for (int k0 = 0; k0 < K; k0 += 16) {
        const float* ap = A + (size_t)(m0+arow)*K + k0 + akq;
        float4 a0 = *(const float4*)ap;
        float4 a1 = *(const float4*)(ap+4);
        float4 bv = make_float4(0.f,0.f,0.f,0.f);
        if (bn < N) {
            const float* bp = B + (size_t)brow_src*ldb + k0 + bkq;
            bv = *(const float4*)bp;
        }
        __syncthreads();
        As[akq+0][g_arow]=a0.x; As[akq+1][g_arow]=a0.y; As[akq+2][g_arow]=a0.z; As[akq+3][g_arow]=a0.w;
        As[akq+4][g_arow]=a1.x; As[akq+5][g_arow]=a1.y; As[akq+6][g_arow]=a1.z; As[akq+7][g_arow]=a1.w;
        Bs[bkq+0][brow]=bv.x; Bs[bkq+1][brow]=bv.y; Bs[bkq+2][brow]=bv.z; Bs[bkq+3][brow]=bv.w;
        __syncthreads();
        #pragma unroll
        for (int kk = 0; kk < 16; ++kk) {
            float4 av0 = *(const float4*)&As[kk][rbase];
            float4 av1 = *(const float4*)&As[kk][rbase+4];
            float4 bvv = *(const float4*)&Bs[kk][tn*4];
            float a[8] = {av0.x,av0.y,av0.z,av0.w,av1.x,av1.y,av1.z,av1.w};
            float b[4] = {bvv.x,bvv.y,bvv.z,bvv.w};
            #pragma unroll
            for (int r=0;r<8;++r){
                #pragma unroll
                for (int c=0;c<4;++c)
                    acc[r][c] = fmaf(a[r], b[c], acc[r][c]);
            }
        }
    }
    float bias[4];
    #pragma unroll
    for (int c=0;c<4;++c) {
        int n = n0 + tn*4 + c;
        int nsrc = permflag ? ((n & 3)*128 + (n >> 2)) : n;
        float v = 0.f;
        if (n < N) {
            if (ba) v += ba[nsrc];
            if (bb) v += bb[nsrc];
        }
        bias[c] = v;
    }
    #pragma unroll
    for (int r=0;r<8;++r) {
        int m = m0 + tm*8 + r;
        float v[4];
        #pragma unroll
        for (int c=0;c<4;++c) {
            float t = acc[r][c] + bias[c];
            if (expflag) t = fexp2(fminf(fmaxf(t,-40.f),40.f)*2.8853900817779268f); // e^{2t}
            v[c] = t;
        }
        int n = n0 + tn*4;
        if (n + 3 < N) {
            float4 st; st.x=v[0]; st.y=v[1]; st.z=v[2]; st.w=v[3];
            *(float4*)&C[(size_t)m*ldc + n] = st;
        } else {
            #pragma unroll
            for (int c=0;c<4;++c) if (n+c < N) C[(size_t)m*ldc + n + c] = v[c];
        }
    }
}

// ---------------- LSTM: one block per (b, dir); round-3 map + f16 dot2 core ---------------
// Thread t: gate g = t&3 (pytorch order i,f,g,o), row r = t>>2. Weights: wpack f16 pairs,
// 64 uints/thread (contiguous). h kept in LDS as f16; dot = 64 v_dot2_f32_f16 (f32 accum).
// Rationale (rounds 2-8): the allocator refuses to keep a 128-reg fp32 weight array
// resident and streams it from L2 every step (~1850 cy/step = the whole kernel time).
// f16 halves the stream if remat persists, and 64 regs may fit its ~100-reg comfort zone.
// Gate combine: 4 quad shfls; 1 barrier/step; h double-buffered.
__global__ __launch_bounds__(512, 2)
void lstm_kernel(
    const float* __restrict__ xp,      // [dir][2048][512] permuted cols (col 4r+g <- gate row g*128+r)
    const unsigned* wpk,               // [2][512][64] f16 pairs (no __restrict: remat blocker)
    float* hcat)                       // [16][128][256], no __restrict
{
    const int b = blockIdx.x & 15;
    const int dir = blockIdx.x >> 4;
    const int t = threadIdx.x;
    const int gate = t & 3, r = t >> 2;
    const int lane = t & 63, qbase = lane & ~3;
    // activation constants: sig(x)=1/(1+2^(-x*log2e)); tanh(x)=1-2/(1+2^(2x*log2e))
    const float kexp = (gate == 2) ? 2.8853900817779268f : -1.4426950408889634f;
    const float mA   = (gate == 2) ? -2.f : 1.f;
    const float mB   = (gate == 2) ?  1.f : 0.f;

    h2 w[64];
    {
        const unsigned* wr = wpk + ((size_t)dir*512 + t)*64;
        #pragma unroll
        for (int j = 0; j < 64; j += 4) {
            uint4 u = *(const uint4*)(wr + j);
            w[j+0] = __builtin_bit_cast(h2, u.x);
            w[j+1] = __builtin_bit_cast(h2, u.y);
            w[j+2] = __builtin_bit_cast(h2, u.z);
            w[j+3] = __builtin_bit_cast(h2, u.w);
        }
    }

    __shared__ _Float16 h_lds[2][128];
    float c = 0.f;
    if (t < 128) h_lds[0][t] = (_Float16)0.f;
    __syncthreads();

    const float* xpd = xp + (size_t)dir*(2048*512) + (size_t)b*(128*512);
    float xpv = xpd[(dir ? 127 : 0)*512 + t];
    for (int s = 0; s < 128; ++s) {
        const int ts = dir ? (127 - s) : s;
        // branchless prefetch of next step's xp (clamped; last-iter load is harmless)
        const int tsn = dir ? (126 - s < 0 ? 0 : 126 - s) : (s + 1 > 127 ? 127 : s + 1);
        float xnext = xpd[tsn*512 + t];
        const uint4* hb = (const uint4*)&h_lds[s & 1][0];   // 16 x b128 broadcast reads
        float A0=0.f, A1=0.f, A2=0.f, A3=0.f;
        #pragma unroll
        for (int j = 0; j < 16; ++j) {
            uint4 u = hb[j];                                // halfs 8j..8j+7
            A0 = FDOT2(w[4*j+0], __builtin_bit_cast(h2, u.x), A0);
            A1 = FDOT2(w[4*j+1], __builtin_bit_cast(h2, u.y), A1);
            A2 = FDOT2(w[4*j+2], __builtin_bit_cast(h2, u.z), A2);
            A3 = FDOT2(w[4*j+3], __builtin_bit_cast(h2, u.w), A3);
        }
        float dot = xpv + ((A0+A1)+(A2+A3));
        // activated gate value (sig for i,f,o; tanh for g)
        float act = fmaf(mA, frcp(1.f + fexp2(kexp*dot)), mB);
        // quad broadcast: every lane of the quad gets all 4 activated gates of row r
        float i_ = __shfl(act, qbase+0, 64);
        float f_ = __shfl(act, qbase+1, 64);
        float g_ = __shfl(act, qbase+2, 64);
        float o_ = __shfl(act, qbase+3, 64);
        c = f_*c + i_*g_;                  // redundant in all 4 lanes, consistent
        float h = o_ * tanh_(c);
        if (gate == 0) {
            h_lds[(s & 1) ^ 1][r] = (_Float16)h;
            hcat[((size_t)b*128 + ts)*256 + dir*128 + r] = h;
        }
        xpv = xnext;
        __syncthreads();
    }
}

// ------------- pairwise scorer: out[(i*128+j)*16+b] = S + sum_k w2_k / (ea_ik*eb_jk + 1) ----
// w2[k] = -2*fc2_w[k], S = sum(fc2_w)+fc2_b computed in-block (prep fused).
__global__ __launch_bounds__(256) void pair_kernel(
    const float* __restrict__ ea, const float* __restrict__ eb,
    const float* __restrict__ fc2w, const float* __restrict__ fc2b,
    float* __restrict__ out)
{
    __shared__ float eas[32][100];
    __shared__ float ebs[32][100];
    __shared__ float w2s[100];
    __shared__ float red[128];
    const int it = blockIdx.x * 32, jt = blockIdx.y * 32, b = blockIdx.z;
    const int tx = threadIdx.x;
    const float* eab = ea + (size_t)b*12800;
    const float* ebb = eb + (size_t)b*12800;
    for (int idx = tx; idx < 3200; idx += 256) {
        int r = idx / 100;
        int cc = idx - r*100;
        eas[r][cc] = eab[(it + r)*100 + cc];
        ebs[r][cc] = ebb[(jt + r)*100 + cc];
    }
    if (tx < 128) {
        float wv = (tx < 100) ? fc2w[tx] : 0.f;
        if (tx < 100) w2s[tx] = -2.f*wv;
        red[tx] = wv;
    }
    __syncthreads();
    for (int s2 = 64; s2 > 0; s2 >>= 1) {
        if (tx < s2) red[tx] += red[tx+s2];
        __syncthreads();
    }
    const float S = red[0] + fc2b[0];
    const int jp = tx & 15, ip = tx >> 4;
    const int i0 = ip*2, j0 = jp*2;
    float acc00=S, acc01=S, acc10=S, acc11=S;
    #pragma unroll
    for (int k = 0; k < 100; k += 4) {
        float4 A0 = *(const float4*)&eas[i0][k];
        float4 A1 = *(const float4*)&eas[i0+1][k];
        float4 B0 = *(const float4*)&ebs[j0][k];
        float4 B1 = *(const float4*)&ebs[j0+1][k];
        float4 W  = *(const float4*)&w2s[k];
        acc00 = fmaf(W.x, frcp(fmaf(A0.x,B0.x,1.f)), acc00);
        acc01 = fmaf(W.x, frcp(fmaf(A0.x,B1.x,1.f)), acc01);
        acc10 = fmaf(W.x, frcp(fmaf(A1.x,B0.x,1.f)), acc10);
        acc11 = fmaf(W.x, frcp(fmaf(A1.x,B1.x,1.f)), acc11);
        acc00 = fmaf(W.y, frcp(fmaf(A0.y,B0.y,1.f)), acc00);
        acc01 = fmaf(W.y, frcp(fmaf(A0.y,B1.y,1.f)), acc01);
        acc10 = fmaf(W.y, frcp(fmaf(A1.y,B0.y,1.f)), acc10);
        acc11 = fmaf(W.y, frcp(fmaf(A1.y,B1.y,1.f)), acc11);
        acc00 = fmaf(W.z, frcp(fmaf(A0.z,B0.z,1.f)), acc00);
        acc01 = fmaf(W.z, frcp(fmaf(A0.z,B1.z,1.f)), acc01);
        acc10 = fmaf(W.z, frcp(fmaf(A1.z,B0.z,1.f)), acc10);
        acc11 = fmaf(W.z, frcp(fmaf(A1.z,B1.z,1.f)), acc11);
        acc00 = fmaf(W.w, frcp(fmaf(A0.w,B0.w,1.f)), acc00);
        acc01 = fmaf(W.w, frcp(fmaf(A0.w,B1.w,1.f)), acc01);
        acc10 = fmaf(W.w, frcp(fmaf(A1.w,B0.w,1.f)), acc10);
        acc11 = fmaf(W.w, frcp(fmaf(A1.w,B1.w,1.f)), acc11);
    }
    const int gi0 = it + i0, gj0 = jt + j0;
    out[((size_t)(gi0  )*128 + gj0  )*16 + b] = acc00;
    out[((size_t)(gi0  )*128 + gj0+1)*16 + b] = acc01;
    out[((size_t)(gi0+1)*128 + gj0  )*16 + b] = acc10;
    out[((size_t)(gi0+1)*128 + gj0+1)*16 + b] = acc11;
}

extern "C" void kernel_launch(void* const* d_in, const int* in_sizes, int n_in,
                              void* d_out, int out_size, void* d_ws, size_t ws_size,
                              hipStream_t stream)
{
    (void)in_sizes; (void)n_in; (void)out_size; (void)ws_size;
    const int*   widx = (const int*)d_in[0];
    const int*   pidx = (const int*)d_in[1];
    const float* wemb = (const float*)d_in[4];
    const float* temb = (const float*)d_in[5];
    const float* w_ih_l0f = (const float*)d_in[6];
    const float* w_hh_l0f = (const float*)d_in[7];
    const float* b_ih_l0f = (const float*)d_in[8];
    const float* b_hh_l0f = (const float*)d_in[9];
    const float* w_ih_l0b = (const float*)d_in[10];
    const float* w_hh_l0b = (const float*)d_in[11];
    const float* b_ih_l0b = (const float*)d_in[12];
    const float* b_hh_l0b = (const float*)d_in[13];
    const float* w_ih_l1f = (const float*)d_in[14];
    const float* w_hh_l1f = (const float*)d_in[15];
    const float* b_ih_l1f = (const float*)d_in[16];
    const float* b_hh_l1f = (const float*)d_in[17];
    const float* w_ih_l1b = (const float*)d_in[18];
    const float* w_hh_l1b = (const float*)d_in[19];
    const float* b_ih_l1b = (const float*)d_in[20];
    const float* b_hh_l1b = (const float*)d_in[21];
    const float* fc1_w = (const float*)d_in[22];
    const float* fc1_b = (const float*)d_in[23];
    const float* fc2_w = (const float*)d_in[24];
    const float* fc2_b = (const float*)d_in[25];

    float* ws  = (float*)d_ws;
    float* x   = ws;                  // 262144
    float* xp0 = x + 262144;          // 2 * 1048576
    float* h1  = xp0 + 2097152;       // 524288
    float* xp1 = h1 + 524288;         // 2 * 1048576
    float* h2  = xp1 + 2097152;       // 524288
    float* ea  = h2 + 524288;         // 204800
    float* eb  = ea + 204800;         // 204800
    unsigned* wpk0 = (unsigned*)(eb + 204800);   // 65536 uints (layer0 f16 weights)
    unsigned* wpk1 = wpk0 + 65536;               // 65536 uints (layer1)
    // total ~6.1M floats ~= 24.5 MB

    embed_kernel<<<1024, 256, 0, stream>>>(widx, pidx, wemb, temb, x);
    pack_kernel<<<256, 256, 0, stream>>>(w_hh_l0f, w_hh_l0b, wpk0);
    pack_kernel<<<256, 256, 0, stream>>>(w_hh_l1f, w_hh_l1b, wpk1);
    // layer 0 input projections (both dirs in grid.z), gate-permuted columns
    gemm_kernel<<<dim3(16,8,2), 256, 0, stream>>>(x, 128,
        w_ih_l0f, w_ih_l0b, 128,
        b_ih_l0f, b_hh_l0f, b_ih_l0b, b_hh_l0b,
        xp0, xp0 + 1048576, 512, 512, 0, 1);
    lstm_kernel<<<32, 512, 0, stream>>>(xp0, wpk0, h1);
    // layer 1 input projections, gate-permuted columns
    gemm_kernel<<<dim3(16,8,2), 256, 0, stream>>>(h1, 256,
        w_ih_l1f, w_ih_l1b, 256,
        b_ih_l1f, b_hh_l1f, b_ih_l1b, b_hh_l1b,
        xp1, xp1 + 1048576, 512, 512, 0, 1);
    lstm_kernel<<<32, 512, 0, stream>>>(xp1, wpk1, h2);
    // fc1: a = h2@wa^T -> ea = exp(2a); bp = h2@wb^T + fc1_b -> eb = exp(2bp)
    gemm_kernel<<<dim3(16,2,2), 256, 0, stream>>>(h2, 256,
        fc1_w, fc1_w + 256, 512,
        nullptr, nullptr, fc1_b, nullptr,
        ea, eb, 100, 100, 1, 0);
    pair_kernel<<<dim3(4,4,16), 256, 0, stream>>>(ea, eb, fc2_w, fc2_b, (float*)d_out);
}